// Round 3
// baseline (3174.868 us; speedup 1.0000x reference)
//
#include <hip/hip_runtime.h>
#include <hip/hip_bf16.h>
#include <math.h>

// ---------------------------------------------------------------------------
// GCAModel forward, decomposed (all f32 this round):
//   B=16 CDD=5 HIS=50 S=20 T=41 E=300 F=256 H=16 DV=16 QD=200
//   fusion = [cdd(0..19) | SEP@20 | his(21..40)]
// Sharing exploited:
//   XC [80][20][256]  : conv out t=0..19 (cdd-only, per (b,c))
//   XH [800][20][256] : conv out t=21..40 (his-only, per (b,h))
//   XM [4000][256]    : conv out t=20 (mixed, per pair)
//   QC  = XC @ Wq[h] + bq  (q rows t<=19)
//   QC2 = XC @ Wq[h]^T     (for his-row x cdd-col scores)
//   QM  = XM @ Wq[h] + bq  (q row t=20)
//   BQC[h][m] = bq[h].XC[m] (bias term for CR2)
//   score blocks (all precomputed, main attn kernel is load+softmax+PV):
//     SCC = QC.XC^T, CR1 = QC.XH^T, CR2 = XH.QC2^T + BQC,
//     SRC = QM.XC^T, SCX = QC.XM^T,
//     SHX[bh][h][25][25] = [XH@Wq+bq ; QM rows] . [XH ; XM rows]^T (fused in k_shx)
//   xv = x @ Wv_r + bv (bias fold exact: softmax rows sum to 1)
//   VAL = P @ xv per head; word-attn k=tanh(VAL@Wk+bk), w=softmax(k.qw*SCALE),
//   REP = w^T VAL; final: mean over HIS, .Wl+bl, log_softmax over CDD.
// ---------------------------------------------------------------------------

#define SCALE_C 0.05773502691896258f   // 1/sqrt(300)

// -------- static workspace (floats) --------
static constexpr long OFF_XC   = 0L;          // 80*20*256      = 409600
static constexpr long OFF_XH   = 409600L;     // 800*20*256     = 4096000
static constexpr long OFF_XM   = 4505600L;    // 4000*256       = 1024000
static constexpr long OFF_QC   = 5529600L;    // 16*1600*256    = 6553600
static constexpr long OFF_QC2  = 12083200L;   // 16*1600*256    = 6553600
static constexpr long OFF_QM   = 18636800L;   // 16*4000*256    = 16384000
static constexpr long OFF_BQC  = 35020800L;   // 16*1600        = 25600
static constexpr long OFF_WVR  = 35046400L;   // 256*256        = 65536
static constexpr long OFF_XVC  = 35111936L;   // 1600*256       = 409600
static constexpr long OFF_XVH  = 35521536L;   // 16000*256      = 4096000
static constexpr long OFF_XVM  = 39617536L;   // 4000*256       = 1024000
static constexpr long OFF_SCC  = 40641536L;   // 256*100*100    = 2560000
static constexpr long OFF_CR1  = 43201536L;   // 256*100*1000   = 25600000
static constexpr long OFF_CR2  = 68801536L;   // 256*1000*100   = 25600000
static constexpr long OFF_SRC  = 94401536L;   // 1280*50*20     = 1280000
static constexpr long OFF_SCX  = 95681536L;   // 1280*20*50     = 1280000
static constexpr long OFF_SHX  = 96961536L;   // 12800*625      = 8000000
static constexpr long OFF_VAL  = 104961536L;  // 4000*41*256    = 41984000
static constexpr long OFF_REP  = 146945536L;  // 4000*256       = 1024000
static constexpr long TOTAL_F  = 147969536L;  // ~592 MB

__device__ __align__(16) float g_buf[TOTAL_F];

// -------- Wv rearrange: WVR[g][h*16+d] = Wv[h][g][d] --------
__global__ __launch_bounds__(256) void k_wvr(const float* __restrict__ Wv)
{
    int i = blockIdx.x * 256 + threadIdx.x;      // 65536
    int g = i >> 8, n = i & 255;
    int h = n >> 4, d = n & 15;
    g_buf[OFF_WVR + i] = Wv[((long)h * 256 + g) * 16 + d];
}

// -------- conv (k=3, SAME, relu).  types: A=cdd rows, B=his rows, C=mixed row 20
__global__ __launch_bounds__(256) void k_conv(const int* __restrict__ cand,
                                              const int* __restrict__ clk,
                                              const float* __restrict__ emb,
                                              const float* __restrict__ W,
                                              const float* __restrict__ cbias)
{
    __shared__ float se[22][300];
    const int bid = blockIdx.x, tid = threadIdx.x;
    int type, nrows, nctx;
    int b = 0, bc = 0, bh = 0, h0 = 0;
    if (bid < 80)       { type = 0; bc = bid;      b = bc / 5; nrows = 20; nctx = 22; }
    else if (bid < 880) { type = 1; bh = bid - 80;             nrows = 20; nctx = 22; }
    else { type = 2; int g = bid - 880; bc = g / 5; h0 = (g % 5) * 10; b = bc / 5; nrows = 10; nctx = 12; }

    for (int f = tid; f < nctx * 300; f += 256) {
        int r = f / 300, e = f - r * 300;
        int tok;
        if (type == 0)      tok = (r < 20) ? cand[bc * 20 + r] : (r == 20 ? 1 : -1);
        else if (type == 1) tok = (r == 0) ? 1 : (r <= 20 ? clk[bh * 20 + r - 1] : -1);
        else                tok = (r == 0) ? cand[bc * 20 + 19] : (r == 1 ? 1 : clk[((b * 50) + h0 + (r - 2)) * 20]);
        se[r][e] = (tok < 0) ? 0.0f : emb[(long)tok * 300 + e];
    }
    __syncthreads();

    const int lane = tid & 63, w = tid >> 6;
    int co[5][3];
    #pragma unroll
    for (int q = 0; q < 5; ++q) {
        int r = w + 4 * q; int rr = (r < nrows) ? r : 0;
        #pragma unroll
        for (int dt = 0; dt < 3; ++dt) {
            int idx;
            if (type == 0)      idx = (rr + dt == 0) ? 21 : rr + dt - 1;
            else if (type == 1) idx = rr + dt;
            else                idx = (dt == 0) ? 0 : (dt == 1 ? 1 : 2 + rr);
            co[q][dt] = idx;
        }
    }
    float acc[5][4] = {};
    for (int dt = 0; dt < 3; ++dt) {
        const float* wb = W + (long)(dt * 300) * 256 + lane * 4;
        for (int e = 0; e < 300; ++e) {
            float4 w4 = *(const float4*)(wb + (long)e * 256);
            #pragma unroll
            for (int q = 0; q < 5; ++q) {
                float a = se[co[q][dt]][e];
                acc[q][0] = fmaf(a, w4.x, acc[q][0]);
                acc[q][1] = fmaf(a, w4.y, acc[q][1]);
                acc[q][2] = fmaf(a, w4.z, acc[q][2]);
                acc[q][3] = fmaf(a, w4.w, acc[q][3]);
            }
        }
    }
    float4 b4 = *(const float4*)&cbias[lane * 4];
    #pragma unroll
    for (int q = 0; q < 5; ++q) {
        int r = w + 4 * q;
        if (r < nrows) {
            float4 o;
            o.x = fmaxf(acc[q][0] + b4.x, 0.f);
            o.y = fmaxf(acc[q][1] + b4.y, 0.f);
            o.z = fmaxf(acc[q][2] + b4.z, 0.f);
            o.w = fmaxf(acc[q][3] + b4.w, 0.f);
            long row;
            if (type == 0)      row = OFF_XC + ((long)bc * 20 + r) * 256;
            else if (type == 1) row = OFF_XH + ((long)bh * 20 + r) * 256;
            else                row = OFF_XM + ((long)(bc * 50 + h0 + r)) * 256;
            *(float4*)&g_buf[row + lane * 4] = o;
        }
    }
}

// -------- generic K=256 GEMM, C = A @ B (+colbias), TB: C = A @ B^T --------
// z decomposes as head = z&15, zo = z>>4.  A always in g_buf; B external or g_buf.
template<bool TB>
__global__ __launch_bounds__(256) void gemm_k256(
    long aOff, long aZH, long aZB,
    const float* Bext, long bOff, long bZH, long bZB,
    const float* biasExt, long biasOff, int biasKind, long sZH, long sZB,
    long cOff, long cZ, int ldc, int M, int N)
{
    const int z = blockIdx.z, head = z & 15, zo = z >> 4;
    const float* A = g_buf + aOff + (long)head * aZH + (long)zo * aZB;
    const float* B = (Bext ? Bext : (const float*)(g_buf + bOff)) + (long)head * bZH + (long)zo * bZB;
    const float* bias = nullptr;
    if (biasKind == 1)      bias = biasExt + (long)head * sZH + (long)zo * sZB;
    else if (biasKind == 2) bias = g_buf + biasOff + (long)head * sZH + (long)zo * sZB;
    float* C = g_buf + cOff + (long)z * cZ;

    const int m0 = blockIdx.x << 6, n0 = blockIdx.y << 6;
    __shared__ __align__(16) float As[32][68];
    __shared__ __align__(16) float Bs[32][68];
    const int tid = threadIdx.x;
    const int tx = tid & 15, ty = tid >> 4;
    float acc[4][4] = {};

    for (int kk = 0; kk < 256; kk += 32) {
        {   // stage A transposed: As[k][m]
            int m = tid >> 2, ks = (tid & 3) << 3;
            int row = m0 + m; if (row > M - 1) row = M - 1;
            const float* ap = A + (long)row * 256 + kk + ks;
            float4 v0 = *(const float4*)ap;
            float4 v1 = *(const float4*)(ap + 4);
            As[ks + 0][m] = v0.x; As[ks + 1][m] = v0.y; As[ks + 2][m] = v0.z; As[ks + 3][m] = v0.w;
            As[ks + 4][m] = v1.x; As[ks + 5][m] = v1.y; As[ks + 6][m] = v1.z; As[ks + 7][m] = v1.w;
        }
        if (TB) {   // B rows are N x 256 row-major -> Bs[k][n]
            int n = tid >> 2, ks = (tid & 3) << 3;
            int col = n0 + n; if (col > N - 1) col = N - 1;
            const float* bp = B + (long)col * 256 + kk + ks;
            float4 v0 = *(const float4*)bp;
            float4 v1 = *(const float4*)(bp + 4);
            Bs[ks + 0][n] = v0.x; Bs[ks + 1][n] = v0.y; Bs[ks + 2][n] = v0.z; Bs[ks + 3][n] = v0.w;
            Bs[ks + 4][n] = v1.x; Bs[ks + 5][n] = v1.y; Bs[ks + 6][n] = v1.z; Bs[ks + 7][n] = v1.w;
        } else {    // B is 256 x 256 row-major
            int k = tid >> 3, ns = (tid & 7) << 3;
            const float* bp = B + (long)(kk + k) * 256 + n0 + ns;
            float4 v0 = *(const float4*)bp;
            float4 v1 = *(const float4*)(bp + 4);
            float* d = &Bs[k][ns];
            d[0] = v0.x; d[1] = v0.y; d[2] = v0.z; d[3] = v0.w;
            d[4] = v1.x; d[5] = v1.y; d[6] = v1.z; d[7] = v1.w;
        }
        __syncthreads();
        #pragma unroll
        for (int k = 0; k < 32; ++k) {
            float4 a4 = *(const float4*)&As[k][ty << 2];
            float4 b4 = *(const float4*)&Bs[k][tx << 2];
            float av[4] = {a4.x, a4.y, a4.z, a4.w};
            float bv_[4] = {b4.x, b4.y, b4.z, b4.w};
            #pragma unroll
            for (int i = 0; i < 4; ++i)
                #pragma unroll
                for (int j = 0; j < 4; ++j)
                    acc[i][j] = fmaf(av[i], bv_[j], acc[i][j]);
        }
        __syncthreads();
    }
    float cb[4] = {0.f, 0.f, 0.f, 0.f};
    if (bias) {
        #pragma unroll
        for (int j = 0; j < 4; ++j) { int col = n0 + (tx << 2) + j; if (col < N) cb[j] = bias[col]; }
    }
    #pragma unroll
    for (int i = 0; i < 4; ++i) {
        int row = m0 + (ty << 2) + i;
        if (row < M) {
            #pragma unroll
            for (int j = 0; j < 4; ++j) {
                int col = n0 + (tx << 2) + j;
                if (col < N) C[(long)row * ldc + col] = acc[i][j] + cb[j];
            }
        }
    }
}

// -------- BQC[h][m] = bq[h] . XC[m] --------
__global__ __launch_bounds__(256) void k_bq(const float* __restrict__ bq)
{
    __shared__ float sbq[16][260];
    const int tid = threadIdx.x;
    for (int i = tid; i < 4096; i += 256) sbq[i >> 8][i & 255] = bq[i];
    __syncthreads();
    const int mm = tid >> 4, hh = tid & 15;
    const int m = blockIdx.x * 16 + mm;
    const float* x = &g_buf[OFF_XC + (long)m * 256];
    float s = 0.f;
    for (int g = 0; g < 256; g += 4) {
        float4 xv = *(const float4*)&x[g];
        s = fmaf(sbq[hh][g], xv.x, s);
        s = fmaf(sbq[hh][g + 1], xv.y, s);
        s = fmaf(sbq[hh][g + 2], xv.z, s);
        s = fmaf(sbq[hh][g + 3], xv.w, s);
    }
    g_buf[OFF_BQC + (long)hh * 1600 + m] = s;
}

// -------- fused: per (b,h) compute Q = XH@Wq[h]+bq, extended Gram vs [XH;XM] ----
// SHX[bh][head][25][25]: rows 0..19 = q(t=21..40), rows 20..24 = q(t=20) per c;
//                        cols 0..19 = x(s=21..40), cols 20..24 = x(s=20) per c.
__global__ __launch_bounds__(256) void k_shx(const float* __restrict__ Wq,
                                             const float* __restrict__ bq)
{
    const int bh = blockIdx.x;
    const int b = bh / 50, h = bh % 50;
    __shared__ __align__(16) float sx[25][260];
    __shared__ __align__(16) float sq[25][260];
    __shared__ __align__(16) float swq[16][256];
    const int tid = threadIdx.x;
    for (int i = tid; i < 25 * 256; i += 256) {
        int r = i >> 8, e = i & 255;
        float v;
        if (r < 20) v = g_buf[OFF_XH + ((long)bh * 20 + r) * 256 + e];
        else        v = g_buf[OFF_XM + ((long)((b * 5 + (r - 20)) * 50 + h)) * 256 + e];
        sx[r][e] = v;
    }
    __syncthreads();
    const int tx = tid & 63, ty = tid >> 6;
    for (int head = 0; head < 16; ++head) {
        float acc[5][4] = {};
        for (int kk = 0; kk < 256; kk += 16) {
            __syncthreads();
            {   // stage Wq chunk
                int k = tid >> 4, n16 = (tid & 15) << 4;
                const float4* src = (const float4*)(Wq + ((long)head * 256 + kk + k) * 256 + n16);
                float4* dst = (float4*)&swq[k][n16];
                dst[0] = src[0]; dst[1] = src[1]; dst[2] = src[2]; dst[3] = src[3];
            }
            __syncthreads();
            for (int k = 0; k < 16; ++k) {
                float4 b4 = *(const float4*)&swq[k][tx * 4];
                #pragma unroll
                for (int r = 0; r < 5; ++r) {
                    float a = sx[ty * 5 + r][kk + k];
                    acc[r][0] = fmaf(a, b4.x, acc[r][0]);
                    acc[r][1] = fmaf(a, b4.y, acc[r][1]);
                    acc[r][2] = fmaf(a, b4.z, acc[r][2]);
                    acc[r][3] = fmaf(a, b4.w, acc[r][3]);
                }
            }
        }
        // write q rows (+bias), load QM rows (q at t=20, bias already included)
        #pragma unroll
        for (int r = 0; r < 5; ++r)
            #pragma unroll
            for (int j = 0; j < 4; ++j)
                sq[ty * 5 + r][tx * 4 + j] = acc[r][j] + bq[head * 256 + tx * 4 + j];
        for (int i = tid; i < 5 * 256; i += 256) {
            int r = i >> 8, e = i & 255;
            sq[20 + r][e] = g_buf[OFF_QM + ((long)head * 4000 + (long)(b * 5 + r) * 50 + h) * 256 + e];
        }
        __syncthreads();
        {
            int j = tid & 31, i0 = tid >> 5;
            if (j < 25) {
                for (int i = i0; i < 25; i += 8) {
                    float s = 0.f;
                    for (int k = 0; k < 256; k += 4) {
                        float4 qa = *(const float4*)&sq[i][k];
                        float4 xb = *(const float4*)&sx[j][k];
                        s = fmaf(qa.x, xb.x, fmaf(qa.y, xb.y, fmaf(qa.z, xb.z, fmaf(qa.w, xb.w, s))));
                    }
                    g_buf[OFF_SHX + ((long)bh * 16 + head) * 625 + i * 25 + j] = s;
                }
            }
        }
        __syncthreads();
    }
}

// -------- per-pair attention: assemble scores (pure loads), softmax, P@xv ----
__global__ __launch_bounds__(256) void k_attn()
{
    const int p = blockIdx.x;
    const int b = p / 250;
    const int c = (p / 50) % 5;
    const int h = p % 50;
    const int bc = b * 5 + c;
    const int bh = b * 50 + h;
    __shared__ float ssc[41][44];
    __shared__ float sxv[41][16];
    const int tid = threadIdx.x;
    for (int head = 0; head < 16; ++head) {
        const long z  = b * 16 + head;
        const long zc = bc * 16 + head;
        const long zh = (long)bh * 16 + head;
        for (int i = tid; i < 41 * 16; i += 256) {
            int r = i >> 4, d = i & 15;
            float v;
            if (r < 20)       v = g_buf[OFF_XVC + ((long)bc * 20 + r) * 256 + head * 16 + d];
            else if (r == 20) v = g_buf[OFF_XVM + (long)p * 256 + head * 16 + d];
            else              v = g_buf[OFF_XVH + ((long)bh * 20 + (r - 21)) * 256 + head * 16 + d];
            sxv[r][d] = v;
        }
        for (int i = tid; i < 1681; i += 256) {
            int t = i / 41, s = i - t * 41;
            float v;
            if (t < 20) {
                if (s < 20)       v = g_buf[OFF_SCC + z * 10000 + (c * 20 + t) * 100 + (c * 20 + s)];
                else if (s == 20) v = g_buf[OFF_SCX + zc * 1000 + t * 50 + h];
                else              v = g_buf[OFF_CR1 + z * 100000 + (long)(c * 20 + t) * 1000 + h * 20 + (s - 21)];
            } else if (t == 20) {
                if (s < 20)       v = g_buf[OFF_SRC + zc * 1000 + h * 20 + s];
                else              v = g_buf[OFF_SHX + zh * 625 + (20 + c) * 25 + ((s == 20) ? (20 + c) : (s - 21))];
            } else {
                if (s < 20)       v = g_buf[OFF_CR2 + z * 100000 + (long)(h * 20 + (t - 21)) * 100 + (c * 20 + s)];
                else              v = g_buf[OFF_SHX + zh * 625 + (t - 21) * 25 + ((s == 20) ? (20 + c) : (s - 21))];
            }
            ssc[t][s] = v * SCALE_C;
        }
        __syncthreads();
        if (tid < 41) {
            float m = -1e30f;
            for (int s2 = 0; s2 < 41; ++s2) m = fmaxf(m, ssc[tid][s2]);
            float sum = 0.f;
            for (int s2 = 0; s2 < 41; ++s2) { float e = __expf(ssc[tid][s2] - m); ssc[tid][s2] = e; sum += e; }
            float inv = 1.f / sum;
            for (int s2 = 0; s2 < 41; ++s2) ssc[tid][s2] *= inv;
        }
        __syncthreads();
        {
            const int t0 = tid >> 4, d = tid & 15;
            for (int t = t0; t < 41; t += 16) {
                float a = 0.f;
                for (int s2 = 0; s2 < 41; ++s2) a = fmaf(ssc[t][s2], sxv[s2][d], a);
                g_buf[OFF_VAL + ((long)p * 41 + t) * 256 + head * 16 + d] = a;
            }
        }
        __syncthreads();
    }
}

// -------- word attention per pair: k=tanh(VAL@Wk+bk); w=softmax(k.qw*SCALE); REP=w^T VAL
__global__ __launch_bounds__(256) void k_wa(const float* __restrict__ Wk,
                                            const float* __restrict__ bk,
                                            const float* __restrict__ qw)
{
    const int p = blockIdx.x, tid = threadIdx.x;
    __shared__ __align__(16) float sval[41 * 256];
    __shared__ float skq[41];
    for (int i = tid; i < 41 * 256; i += 256) sval[i] = g_buf[OFF_VAL + (long)p * 41 * 256 + i];
    __syncthreads();
    const int tx = tid & 63, ty = tid >> 6;
    float acc[11][4] = {};
    for (int dd = 0; dd < 256; ++dd) {
        const float* wr = Wk + (long)dd * 200;
        float w0 = (tx < 200)       ? wr[tx]        : 0.f;
        float w1 = (tx + 64 < 200)  ? wr[tx + 64]   : 0.f;
        float w2 = (tx + 128 < 200) ? wr[tx + 128]  : 0.f;
        float w3 = (tx + 192 < 200) ? wr[tx + 192]  : 0.f;
        #pragma unroll
        for (int k = 0; k < 11; ++k) {
            int t = ty + 4 * k;
            if (t < 41) {
                float a = sval[t * 256 + dd];
                acc[k][0] = fmaf(a, w0, acc[k][0]);
                acc[k][1] = fmaf(a, w1, acc[k][1]);
                acc[k][2] = fmaf(a, w2, acc[k][2]);
                acc[k][3] = fmaf(a, w3, acc[k][3]);
            }
        }
    }
    #pragma unroll
    for (int k = 0; k < 11; ++k) {
        int t = ty + 4 * k;
        float s = 0.f;
        if (t < 41) {
            if (tx < 200)       s += tanhf(acc[k][0] + bk[tx])       * qw[tx];
            if (tx + 64 < 200)  s += tanhf(acc[k][1] + bk[tx + 64])  * qw[tx + 64];
            if (tx + 128 < 200) s += tanhf(acc[k][2] + bk[tx + 128]) * qw[tx + 128];
            if (tx + 192 < 200) s += tanhf(acc[k][3] + bk[tx + 192]) * qw[tx + 192];
        }
        #pragma unroll
        for (int off = 32; off > 0; off >>= 1) s += __shfl_down(s, off, 64);
        if (tx == 0 && t < 41) skq[t] = s;
    }
    __syncthreads();
    if (tid < 64) {
        float v = (tid < 41) ? skq[tid] * SCALE_C : -1e30f;
        float m = v;
        #pragma unroll
        for (int off = 32; off > 0; off >>= 1) m = fmaxf(m, __shfl_xor(m, off, 64));
        float e = (tid < 41) ? __expf(v - m) : 0.f;
        float sum = e;
        #pragma unroll
        for (int off = 32; off > 0; off >>= 1) sum += __shfl_xor(sum, off, 64);
        if (tid < 41) skq[tid] = e / sum;
    }
    __syncthreads();
    {
        float r = 0.f;
        for (int t = 0; t < 41; ++t) r = fmaf(skq[t], sval[t * 256 + tid], r);
        g_buf[OFF_REP + (long)p * 256 + tid] = r;
    }
}

// -------- final: mean over HIS, .Wl + bl, log_softmax over CDD --------
__global__ __launch_bounds__(256) void k_final(const float* __restrict__ Wl,
                                               const float* __restrict__ bl,
                                               float* __restrict__ out)
{
    const int b = blockIdx.x, tid = threadIdx.x;
    __shared__ float ssum[4];
    __shared__ float sc5[5];
    float wl = Wl[tid];
    for (int c = 0; c < 5; ++c) {
        float fv = 0.f;
        const long base = OFF_REP + ((long)(b * 5 + c) * 50) * 256 + tid;
        for (int h = 0; h < 50; ++h) fv += g_buf[base + (long)h * 256];
        float v = fv * (1.0f / 50.0f) * wl;
        #pragma unroll
        for (int off = 32; off > 0; off >>= 1) v += __shfl_down(v, off, 64);
        if ((tid & 63) == 0) ssum[tid >> 6] = v;
        __syncthreads();
        if (tid == 0) sc5[c] = ssum[0] + ssum[1] + ssum[2] + ssum[3] + bl[0];
        __syncthreads();
    }
    if (tid == 0) {
        float m = -1e30f;
        for (int c = 0; c < 5; ++c) m = fmaxf(m, sc5[c]);
        float sum = 0.f;
        for (int c = 0; c < 5; ++c) sum += expf(sc5[c] - m);
        float lse = m + logf(sum);
        for (int c = 0; c < 5; ++c) out[b * 5 + c] = sc5[c] - lse;
    }
}

extern "C" void kernel_launch(void* const* d_in, const int* in_sizes, int n_in,
                              void* d_out, int out_size, void* d_ws, size_t ws_size,
                              hipStream_t stream)
{
    (void)in_sizes; (void)n_in; (void)d_ws; (void)ws_size; (void)out_size;
    const int*   cand  = (const int*)d_in[0];
    const int*   clk   = (const int*)d_in[1];
    const float* emb   = (const float*)d_in[2];
    const float* convw = (const float*)d_in[3];
    const float* convb = (const float*)d_in[4];
    const float* Wq    = (const float*)d_in[5];
    const float* bq    = (const float*)d_in[6];
    const float* Wv    = (const float*)d_in[7];
    const float* bv    = (const float*)d_in[8];
    const float* Wk    = (const float*)d_in[9];
    const float* bk    = (const float*)d_in[10];
    const float* qw    = (const float*)d_in[11];
    const float* Wl    = (const float*)d_in[12];
    const float* bl    = (const float*)d_in[13];
    float* out = (float*)d_out;

    k_wvr <<<256, 256, 0, stream>>>(Wv);
    k_conv<<<1280, 256, 0, stream>>>(cand, clk, emb, convw, convb);

    // projections (K=256 GEMMs)
    gemm_k256<false><<<dim3(25, 4, 16), 256, 0, stream>>>(
        OFF_XC, 0, 0,  Wq, 0, 65536, 0,  bq, 0, 1, 256, 0,  OFF_QC, 409600, 256, 1600, 256);
    gemm_k256<true ><<<dim3(25, 4, 16), 256, 0, stream>>>(
        OFF_XC, 0, 0,  Wq, 0, 65536, 0,  nullptr, 0, 0, 0, 0,  OFF_QC2, 409600, 256, 1600, 256);
    gemm_k256<false><<<dim3(63, 4, 16), 256, 0, stream>>>(
        OFF_XM, 0, 0,  Wq, 0, 65536, 0,  bq, 0, 1, 256, 0,  OFF_QM, 1024000, 256, 4000, 256);
    gemm_k256<false><<<dim3(25, 4, 1), 256, 0, stream>>>(
        OFF_XC, 0, 0,  nullptr, OFF_WVR, 0, 0,  bv, 0, 1, 0, 0,  OFF_XVC, 0, 256, 1600, 256);
    gemm_k256<false><<<dim3(250, 4, 1), 256, 0, stream>>>(
        OFF_XH, 0, 0,  nullptr, OFF_WVR, 0, 0,  bv, 0, 1, 0, 0,  OFF_XVH, 0, 256, 16000, 256);
    gemm_k256<false><<<dim3(63, 4, 1), 256, 0, stream>>>(
        OFF_XM, 0, 0,  nullptr, OFF_WVR, 0, 0,  bv, 0, 1, 0, 0,  OFF_XVM, 0, 256, 4000, 256);
    k_bq<<<100, 256, 0, stream>>>(bq);

    // score blocks (NT GEMMs)
    gemm_k256<true><<<dim3(2, 2, 256), 256, 0, stream>>>(
        OFF_QC, 409600, 25600,  nullptr, OFF_XC, 0, 25600,  nullptr, 0, 0, 0, 0,
        OFF_SCC, 10000, 100, 100, 100);
    gemm_k256<true><<<dim3(2, 16, 256), 256, 0, stream>>>(
        OFF_QC, 409600, 25600,  nullptr, OFF_XH, 0, 256000,  nullptr, 0, 0, 0, 0,
        OFF_CR1, 100000, 1000, 100, 1000);
    gemm_k256<true><<<dim3(16, 2, 256), 256, 0, stream>>>(
        OFF_XH, 0, 256000,  nullptr, OFF_QC2, 409600, 25600,  nullptr, OFF_BQC, 2, 1600, 100,
        OFF_CR2, 100000, 100, 1000, 100);
    gemm_k256<true><<<dim3(1, 1, 1280), 256, 0, stream>>>(
        OFF_QM, 1024000, 12800,  nullptr, OFF_XC, 0, 5120,  nullptr, 0, 0, 0, 0,
        OFF_SRC, 1000, 20, 50, 20);
    gemm_k256<true><<<dim3(1, 1, 1280), 256, 0, stream>>>(
        OFF_QC, 409600, 5120,  nullptr, OFF_XM, 0, 12800,  nullptr, 0, 0, 0, 0,
        OFF_SCX, 1000, 50, 20, 50);
    k_shx<<<800, 256, 0, stream>>>(Wq, bq);

    k_attn <<<4000, 256, 0, stream>>>();
    k_wa   <<<4000, 256, 0, stream>>>(Wk, bk, qw);
    k_final<<<16, 256, 0, stream>>>(Wl, bl, out);
}

// Round 4
// 2457.874 us; speedup vs baseline: 1.2917x; 1.2917x over previous
//
#include <hip/hip_runtime.h>
#include <hip/hip_bf16.h>
#include <math.h>

// ---------------------------------------------------------------------------
// GCAModel forward, decomposed:
//   B=16 CDD=5 HIS=50 S=20 T=41 E=300 F=256 H=16 DV=16 QD=200
//   fusion = [cdd(0..19) | SEP@20 | his(21..40)]
// Sharing exploited:
//   XC [80][20][256]  : conv out t=0..19 (cdd-only, per (b,c))
//   XH [800][20][256] : conv out t=21..40 (his-only, per (b,h))
//   XM [4000][256]    : conv out t=20 (mixed, per pair)
//   QC  = XC @ Wq[h] + bq ; QC2 = XC @ Wq[h]^T ; QM = XM @ Wq[h] + bq
//   BQC[h][m] = bq[h].XC[m]
//   score blocks: SCC = QC.XC^T, CR1 = QC.XH^T, CR2 = XH.QC2^T + BQC,
//     SRC = QM.XC^T, SCX = QC.XM^T,
//     SHX[bh][h][25][25] = (X25@Wq+bq).X25^T  (NEW: bf16 MFMA path,
//       X25 = [XH rows t=21..40 ; XM rows t=20 for c=0..4])
//   xv = x @ Wv_r + bv ; VAL = P @ xv ; word-attn ; mean/LTR/log_softmax.
// ---------------------------------------------------------------------------

#define SCALE_C 0.05773502691896258f   // 1/sqrt(300)

typedef __attribute__((ext_vector_type(4))) float f32x4;
typedef __attribute__((ext_vector_type(8))) short short8;

static __device__ __forceinline__ unsigned short f2bf(float f)
{
    unsigned int u = __builtin_bit_cast(unsigned int, f);
    u = (u + 0x7fffu + ((u >> 16) & 1u)) >> 16;
    return (unsigned short)u;
}

// -------- static workspace (floats) --------
static constexpr long OFF_XC   = 0L;          // 80*20*256      = 409600
static constexpr long OFF_XH   = 409600L;     // 800*20*256     = 4096000
static constexpr long OFF_XM   = 4505600L;    // 4000*256       = 1024000
static constexpr long OFF_QC   = 5529600L;    // 16*1600*256    = 6553600
static constexpr long OFF_QC2  = 12083200L;   // 16*1600*256    = 6553600
static constexpr long OFF_QM   = 18636800L;   // 16*4000*256    = 16384000
static constexpr long OFF_BQC  = 35020800L;   // 16*1600        = 25600
static constexpr long OFF_WVR  = 35046400L;   // 256*256        = 65536
static constexpr long OFF_XVC  = 35111936L;   // 1600*256       = 409600
static constexpr long OFF_XVH  = 35521536L;   // 16000*256      = 4096000
static constexpr long OFF_XVM  = 39617536L;   // 4000*256       = 1024000
static constexpr long OFF_SCC  = 40641536L;   // 256*100*100    = 2560000
static constexpr long OFF_CR1  = 43201536L;   // 256*100*1000   = 25600000
static constexpr long OFF_CR2  = 68801536L;   // 256*1000*100   = 25600000
static constexpr long OFF_SRC  = 94401536L;   // 1280*50*20     = 1280000
static constexpr long OFF_SCX  = 95681536L;   // 1280*20*50     = 1280000
static constexpr long OFF_SHX  = 96961536L;   // 12800*625      = 8000000
static constexpr long OFF_VAL  = 104961536L;  // 4000*41*256    = 41984000
static constexpr long OFF_REP  = 146945536L;  // 4000*256       = 1024000
static constexpr long TOTAL_F  = 147969536L;  // ~592 MB

__device__ __align__(16) float g_buf[TOTAL_F];

// bf16 side buffers for the MFMA path
// XS: stacked per-bh 25x256 x-rows (rows 20000..20031 zero pad), QS = XS@Wq+bq
__device__ __align__(16) unsigned short g_xs[20032L * 256];        // 10.3 MB
__device__ __align__(16) unsigned short g_wqt[16L * 256 * 256];    // WqT[h][n][k]
__device__ __align__(16) unsigned short g_qs[16L * 20032 * 256];   // 164 MB

// -------- Wv rearrange: WVR[g][h*16+d] = Wv[h][g][d] --------
__global__ __launch_bounds__(256) void k_wvr(const float* __restrict__ Wv)
{
    int i = blockIdx.x * 256 + threadIdx.x;      // 65536
    int g = i >> 8, n = i & 255;
    int h = n >> 4, d = n & 15;
    g_buf[OFF_WVR + i] = Wv[((long)h * 256 + g) * 16 + d];
}

// -------- conv (k=3, SAME, relu).  types: A=cdd rows, B=his rows, C=mixed row 20
__global__ __launch_bounds__(256) void k_conv(const int* __restrict__ cand,
                                              const int* __restrict__ clk,
                                              const float* __restrict__ emb,
                                              const float* __restrict__ W,
                                              const float* __restrict__ cbias)
{
    __shared__ float se[22][300];
    const int bid = blockIdx.x, tid = threadIdx.x;
    int type, nrows, nctx;
    int b = 0, bc = 0, bh = 0, h0 = 0;
    if (bid < 80)       { type = 0; bc = bid;      b = bc / 5; nrows = 20; nctx = 22; }
    else if (bid < 880) { type = 1; bh = bid - 80;             nrows = 20; nctx = 22; }
    else { type = 2; int g = bid - 880; bc = g / 5; h0 = (g % 5) * 10; b = bc / 5; nrows = 10; nctx = 12; }

    for (int f = tid; f < nctx * 300; f += 256) {
        int r = f / 300, e = f - r * 300;
        int tok;
        if (type == 0)      tok = (r < 20) ? cand[bc * 20 + r] : (r == 20 ? 1 : -1);
        else if (type == 1) tok = (r == 0) ? 1 : (r <= 20 ? clk[bh * 20 + r - 1] : -1);
        else                tok = (r == 0) ? cand[bc * 20 + 19] : (r == 1 ? 1 : clk[((b * 50) + h0 + (r - 2)) * 20]);
        se[r][e] = (tok < 0) ? 0.0f : emb[(long)tok * 300 + e];
    }
    __syncthreads();

    const int lane = tid & 63, w = tid >> 6;
    int co[5][3];
    #pragma unroll
    for (int q = 0; q < 5; ++q) {
        int r = w + 4 * q; int rr = (r < nrows) ? r : 0;
        #pragma unroll
        for (int dt = 0; dt < 3; ++dt) {
            int idx;
            if (type == 0)      idx = (rr + dt == 0) ? 21 : rr + dt - 1;
            else if (type == 1) idx = rr + dt;
            else                idx = (dt == 0) ? 0 : (dt == 1 ? 1 : 2 + rr);
            co[q][dt] = idx;
        }
    }
    float acc[5][4] = {};
    for (int dt = 0; dt < 3; ++dt) {
        const float* wb = W + (long)(dt * 300) * 256 + lane * 4;
        for (int e = 0; e < 300; ++e) {
            float4 w4 = *(const float4*)(wb + (long)e * 256);
            #pragma unroll
            for (int q = 0; q < 5; ++q) {
                float a = se[co[q][dt]][e];
                acc[q][0] = fmaf(a, w4.x, acc[q][0]);
                acc[q][1] = fmaf(a, w4.y, acc[q][1]);
                acc[q][2] = fmaf(a, w4.z, acc[q][2]);
                acc[q][3] = fmaf(a, w4.w, acc[q][3]);
            }
        }
    }
    float4 b4 = *(const float4*)&cbias[lane * 4];
    #pragma unroll
    for (int q = 0; q < 5; ++q) {
        int r = w + 4 * q;
        if (r < nrows) {
            float4 o;
            o.x = fmaxf(acc[q][0] + b4.x, 0.f);
            o.y = fmaxf(acc[q][1] + b4.y, 0.f);
            o.z = fmaxf(acc[q][2] + b4.z, 0.f);
            o.w = fmaxf(acc[q][3] + b4.w, 0.f);
            long row;
            if (type == 0)      row = OFF_XC + ((long)bc * 20 + r) * 256;
            else if (type == 1) row = OFF_XH + ((long)bh * 20 + r) * 256;
            else                row = OFF_XM + ((long)(bc * 50 + h0 + r)) * 256;
            *(float4*)&g_buf[row + lane * 4] = o;
        }
    }
}

// -------- generic K=256 GEMM, C = A @ B (+colbias), TB: C = A @ B^T --------
template<bool TB>
__global__ __launch_bounds__(256) void gemm_k256(
    long aOff, long aZH, long aZB,
    const float* Bext, long bOff, long bZH, long bZB,
    const float* biasExt, long biasOff, int biasKind, long sZH, long sZB,
    long cOff, long cZ, int ldc, int M, int N)
{
    const int z = blockIdx.z, head = z & 15, zo = z >> 4;
    const float* A = g_buf + aOff + (long)head * aZH + (long)zo * aZB;
    const float* B = (Bext ? Bext : (const float*)(g_buf + bOff)) + (long)head * bZH + (long)zo * bZB;
    const float* bias = nullptr;
    if (biasKind == 1)      bias = biasExt + (long)head * sZH + (long)zo * sZB;
    else if (biasKind == 2) bias = g_buf + biasOff + (long)head * sZH + (long)zo * sZB;
    float* C = g_buf + cOff + (long)z * cZ;

    const int m0 = blockIdx.x << 6, n0 = blockIdx.y << 6;
    __shared__ __align__(16) float As[32][68];
    __shared__ __align__(16) float Bs[32][68];
    const int tid = threadIdx.x;
    const int tx = tid & 15, ty = tid >> 4;
    float acc[4][4] = {};

    for (int kk = 0; kk < 256; kk += 32) {
        {   // stage A transposed: As[k][m]
            int m = tid >> 2, ks = (tid & 3) << 3;
            int row = m0 + m; if (row > M - 1) row = M - 1;
            const float* ap = A + (long)row * 256 + kk + ks;
            float4 v0 = *(const float4*)ap;
            float4 v1 = *(const float4*)(ap + 4);
            As[ks + 0][m] = v0.x; As[ks + 1][m] = v0.y; As[ks + 2][m] = v0.z; As[ks + 3][m] = v0.w;
            As[ks + 4][m] = v1.x; As[ks + 5][m] = v1.y; As[ks + 6][m] = v1.z; As[ks + 7][m] = v1.w;
        }
        if (TB) {
            int n = tid >> 2, ks = (tid & 3) << 3;
            int col = n0 + n; if (col > N - 1) col = N - 1;
            const float* bp = B + (long)col * 256 + kk + ks;
            float4 v0 = *(const float4*)bp;
            float4 v1 = *(const float4*)(bp + 4);
            Bs[ks + 0][n] = v0.x; Bs[ks + 1][n] = v0.y; Bs[ks + 2][n] = v0.z; Bs[ks + 3][n] = v0.w;
            Bs[ks + 4][n] = v1.x; Bs[ks + 5][n] = v1.y; Bs[ks + 6][n] = v1.z; Bs[ks + 7][n] = v1.w;
        } else {
            int k = tid >> 3, ns = (tid & 7) << 3;
            const float* bp = B + (long)(kk + k) * 256 + n0 + ns;
            float4 v0 = *(const float4*)bp;
            float4 v1 = *(const float4*)(bp + 4);
            float* d = &Bs[k][ns];
            d[0] = v0.x; d[1] = v0.y; d[2] = v0.z; d[3] = v0.w;
            d[4] = v1.x; d[5] = v1.y; d[6] = v1.z; d[7] = v1.w;
        }
        __syncthreads();
        #pragma unroll
        for (int k = 0; k < 32; ++k) {
            float4 a4 = *(const float4*)&As[k][ty << 2];
            float4 b4 = *(const float4*)&Bs[k][tx << 2];
            float av[4] = {a4.x, a4.y, a4.z, a4.w};
            float bv_[4] = {b4.x, b4.y, b4.z, b4.w};
            #pragma unroll
            for (int i = 0; i < 4; ++i)
                #pragma unroll
                for (int j = 0; j < 4; ++j)
                    acc[i][j] = fmaf(av[i], bv_[j], acc[i][j]);
        }
        __syncthreads();
    }
    float cb[4] = {0.f, 0.f, 0.f, 0.f};
    if (bias) {
        #pragma unroll
        for (int j = 0; j < 4; ++j) { int col = n0 + (tx << 2) + j; if (col < N) cb[j] = bias[col]; }
    }
    #pragma unroll
    for (int i = 0; i < 4; ++i) {
        int row = m0 + (ty << 2) + i;
        if (row < M) {
            #pragma unroll
            for (int j = 0; j < 4; ++j) {
                int col = n0 + (tx << 2) + j;
                if (col < N) C[(long)row * ldc + col] = acc[i][j] + cb[j];
            }
        }
    }
}

// -------- BQC[h][m] = bq[h] . XC[m] --------
__global__ __launch_bounds__(256) void k_bq(const float* __restrict__ bq)
{
    __shared__ float sbq[16][260];
    const int tid = threadIdx.x;
    for (int i = tid; i < 4096; i += 256) sbq[i >> 8][i & 255] = bq[i];
    __syncthreads();
    const int mm = tid >> 4, hh = tid & 15;
    const int m = blockIdx.x * 16 + mm;
    const float* x = &g_buf[OFF_XC + (long)m * 256];
    float s = 0.f;
    for (int g = 0; g < 256; g += 4) {
        float4 xv = *(const float4*)&x[g];
        s = fmaf(sbq[hh][g], xv.x, s);
        s = fmaf(sbq[hh][g + 1], xv.y, s);
        s = fmaf(sbq[hh][g + 2], xv.z, s);
        s = fmaf(sbq[hh][g + 3], xv.w, s);
    }
    g_buf[OFF_BQC + (long)hh * 1600 + m] = s;
}

// -------- bf16 conversion: XS (stacked X25 per bh, zero-pad) + WqT --------
__global__ __launch_bounds__(256) void k_cvt(const float* __restrict__ Wq)
{
    long i = (long)blockIdx.x * 256 + threadIdx.x;
    if (i < 5120000L) {                      // XS main: 800*25*256
        int bh = (int)(i / 6400);
        int rem = (int)(i - (long)bh * 6400);
        int r = rem >> 8, e = rem & 255;
        float v;
        if (r < 20) v = g_buf[OFF_XH + ((long)bh * 20 + r) * 256 + e];
        else {
            int b = bh / 50, h = bh % 50;
            v = g_buf[OFF_XM + ((long)((b * 5 + (r - 20)) * 50 + h)) * 256 + e];
        }
        g_xs[i] = f2bf(v);
    } else if (i < 5128192L) {               // pad rows 20000..20031
        g_xs[i] = 0;
    } else if (i < 6176768L) {               // WqT[h][n][k] = Wq[h][k][n]
        long j = i - 5128192L;
        int h = (int)(j >> 16);
        int rem = (int)(j & 65535);
        int n = rem >> 8, k = rem & 255;
        g_wqt[j] = f2bf(Wq[(long)h * 65536 + k * 256 + n]);
    }
}

// -------- MFMA batched GEMM: QS[head] = XS @ Wq[head] + bq (bf16 in/out) ----
// 64x64 tile, 4 waves as 2x2, each wave 32x32 via 2x2 mfma_f32_16x16x32_bf16.
__global__ __launch_bounds__(256) void k_qs(const float* __restrict__ bq)
{
    const int head = blockIdx.z;
    const int m0 = blockIdx.x << 6, n0 = blockIdx.y << 6;
    __shared__ __align__(16) unsigned short Al[64][32];
    __shared__ __align__(16) unsigned short Bl[64][32];
    const int tid = threadIdx.x;
    const int lrow = tid >> 2, lch = (tid & 3) << 3;
    const unsigned short* Ag = g_xs + (long)(m0 + lrow) * 256 + lch;
    const unsigned short* Bg = g_wqt + (long)head * 65536 + (long)(n0 + lrow) * 256 + lch;
    const int w = tid >> 6, lane = tid & 63;
    const int wm = w >> 1, wn = w & 1;
    const int r16 = lane & 15, ko = lane >> 4;

    f32x4 acc00 = {0.f, 0.f, 0.f, 0.f};
    f32x4 acc01 = {0.f, 0.f, 0.f, 0.f};
    f32x4 acc10 = {0.f, 0.f, 0.f, 0.f};
    f32x4 acc11 = {0.f, 0.f, 0.f, 0.f};

    for (int kk = 0; kk < 256; kk += 32) {
        uint4 a = *(const uint4*)(Ag + kk);
        uint4 b = *(const uint4*)(Bg + kk);
        __syncthreads();
        *(uint4*)&Al[lrow][lch] = a;
        *(uint4*)&Bl[lrow][lch] = b;
        __syncthreads();
        short8 av0 = *(const short8*)&Al[wm * 32 + r16][ko * 8];
        short8 av1 = *(const short8*)&Al[wm * 32 + 16 + r16][ko * 8];
        short8 bv0 = *(const short8*)&Bl[wn * 32 + r16][ko * 8];
        short8 bv1 = *(const short8*)&Bl[wn * 32 + 16 + r16][ko * 8];
        acc00 = __builtin_amdgcn_mfma_f32_16x16x32_bf16(av0, bv0, acc00, 0, 0, 0);
        acc01 = __builtin_amdgcn_mfma_f32_16x16x32_bf16(av0, bv1, acc01, 0, 0, 0);
        acc10 = __builtin_amdgcn_mfma_f32_16x16x32_bf16(av1, bv0, acc10, 0, 0, 0);
        acc11 = __builtin_amdgcn_mfma_f32_16x16x32_bf16(av1, bv1, acc11, 0, 0, 0);
    }
    // D layout: col = lane&15, row = (lane>>4)*4 + reg  [measured m89/m91]
    const int n_0 = n0 + wn * 32 + r16;
    const int n_1 = n_0 + 16;
    const float bb0 = bq[head * 256 + n_0];
    const float bb1 = bq[head * 256 + n_1];
    const long qbase = (long)head * 5128192L;
    const int mA = m0 + wm * 32 + ko * 4;        // frag row base, i2=0
    const int mB = mA + 16;                      // i2=1
    #pragma unroll
    for (int reg = 0; reg < 4; ++reg) {
        g_qs[qbase + (long)(mA + reg) * 256 + n_0] = f2bf(acc00[reg] + bb0);
        g_qs[qbase + (long)(mA + reg) * 256 + n_1] = f2bf(acc01[reg] + bb1);
        g_qs[qbase + (long)(mB + reg) * 256 + n_0] = f2bf(acc10[reg] + bb0);
        g_qs[qbase + (long)(mB + reg) * 256 + n_1] = f2bf(acc11[reg] + bb1);
    }
}

// -------- MFMA Gram per bh: SHX[bh][head] = Q25 @ X25^T (same layout as before)
__global__ __launch_bounds__(256) void k_gram()
{
    const int bh = blockIdx.x;
    __shared__ __align__(16) unsigned short Xl[25][264];
    __shared__ __align__(16) unsigned short Ql[25][264];
    const int tid = threadIdx.x;
    for (int i = tid; i < 800; i += 256) {
        int row = i >> 5, c = (i & 31) << 3;
        *(uint4*)&Xl[row][c] = *(const uint4*)(g_xs + ((long)bh * 25 + row) * 256 + c);
    }
    const int w = tid >> 6, lane = tid & 63;
    const int mt = w >> 1, nt = w & 1;
    const int r16 = lane & 15, ko = lane >> 4;
    int ia = mt * 16 + r16; if (ia > 24) ia = 24;   // clamped reads, clipped writes
    int jb = nt * 16 + r16; if (jb > 24) jb = 24;
    const int j = nt * 16 + r16;

    for (int head = 0; head < 16; ++head) {
        __syncthreads();
        for (int i = tid; i < 800; i += 256) {
            int row = i >> 5, c = (i & 31) << 3;
            *(uint4*)&Ql[row][c] =
                *(const uint4*)(g_qs + (long)head * 5128192L + ((long)bh * 25 + row) * 256 + c);
        }
        __syncthreads();
        f32x4 acc = {0.f, 0.f, 0.f, 0.f};
        #pragma unroll
        for (int k0 = 0; k0 < 256; k0 += 32) {
            short8 av = *(const short8*)&Ql[ia][k0 + ko * 8];
            short8 bv = *(const short8*)&Xl[jb][k0 + ko * 8];
            acc = __builtin_amdgcn_mfma_f32_16x16x32_bf16(av, bv, acc, 0, 0, 0);
        }
        if (j < 25) {
            #pragma unroll
            for (int reg = 0; reg < 4; ++reg) {
                int i2 = mt * 16 + ko * 4 + reg;
                if (i2 < 25)
                    g_buf[OFF_SHX + ((long)bh * 16 + head) * 625 + i2 * 25 + j] = acc[reg];
            }
        }
    }
}

// -------- per-pair attention: assemble scores (pure loads), softmax, P@xv ----
__global__ __launch_bounds__(256) void k_attn()
{
    const int p = blockIdx.x;
    const int b = p / 250;
    const int c = (p / 50) % 5;
    const int h = p % 50;
    const int bc = b * 5 + c;
    const int bh = b * 50 + h;
    __shared__ float ssc[41][44];
    __shared__ float sxv[41][16];
    const int tid = threadIdx.x;
    for (int head = 0; head < 16; ++head) {
        const long z  = b * 16 + head;
        const long zc = bc * 16 + head;
        const long zh = (long)bh * 16 + head;
        for (int i = tid; i < 41 * 16; i += 256) {
            int r = i >> 4, d = i & 15;
            float v;
            if (r < 20)       v = g_buf[OFF_XVC + ((long)bc * 20 + r) * 256 + head * 16 + d];
            else if (r == 20) v = g_buf[OFF_XVM + (long)p * 256 + head * 16 + d];
            else              v = g_buf[OFF_XVH + ((long)bh * 20 + (r - 21)) * 256 + head * 16 + d];
            sxv[r][d] = v;
        }
        for (int i = tid; i < 1681; i += 256) {
            int t = i / 41, s = i - t * 41;
            float v;
            if (t < 20) {
                if (s < 20)       v = g_buf[OFF_SCC + z * 10000 + (c * 20 + t) * 100 + (c * 20 + s)];
                else if (s == 20) v = g_buf[OFF_SCX + zc * 1000 + t * 50 + h];
                else              v = g_buf[OFF_CR1 + z * 100000 + (long)(c * 20 + t) * 1000 + h * 20 + (s - 21)];
            } else if (t == 20) {
                if (s < 20)       v = g_buf[OFF_SRC + zc * 1000 + h * 20 + s];
                else              v = g_buf[OFF_SHX + zh * 625 + (20 + c) * 25 + ((s == 20) ? (20 + c) : (s - 21))];
            } else {
                if (s < 20)       v = g_buf[OFF_CR2 + z * 100000 + (long)(h * 20 + (t - 21)) * 100 + (c * 20 + s)];
                else              v = g_buf[OFF_SHX + zh * 625 + (t - 21) * 25 + ((s == 20) ? (20 + c) : (s - 21))];
            }
            ssc[t][s] = v * SCALE_C;
        }
        __syncthreads();
        if (tid < 41) {
            float m = -1e30f;
            for (int s2 = 0; s2 < 41; ++s2) m = fmaxf(m, ssc[tid][s2]);
            float sum = 0.f;
            for (int s2 = 0; s2 < 41; ++s2) { float e = __expf(ssc[tid][s2] - m); ssc[tid][s2] = e; sum += e; }
            float inv = 1.f / sum;
            for (int s2 = 0; s2 < 41; ++s2) ssc[tid][s2] *= inv;
        }
        __syncthreads();
        {
            const int t0 = tid >> 4, d = tid & 15;
            for (int t = t0; t < 41; t += 16) {
                float a = 0.f;
                for (int s2 = 0; s2 < 41; ++s2) a = fmaf(ssc[t][s2], sxv[s2][d], a);
                g_buf[OFF_VAL + ((long)p * 41 + t) * 256 + head * 16 + d] = a;
            }
        }
        __syncthreads();
    }
}

// -------- word attention per pair --------
__global__ __launch_bounds__(256) void k_wa(const float* __restrict__ Wk,
                                            const float* __restrict__ bk,
                                            const float* __restrict__ qw)
{
    const int p = blockIdx.x, tid = threadIdx.x;
    __shared__ __align__(16) float sval[41 * 256];
    __shared__ float skq[41];
    for (int i = tid; i < 41 * 256; i += 256) sval[i] = g_buf[OFF_VAL + (long)p * 41 * 256 + i];
    __syncthreads();
    const int tx = tid & 63, ty = tid >> 6;
    float acc[11][4] = {};
    for (int dd = 0; dd < 256; ++dd) {
        const float* wr = Wk + (long)dd * 200;
        float w0 = (tx < 200)       ? wr[tx]        : 0.f;
        float w1 = (tx + 64 < 200)  ? wr[tx + 64]   : 0.f;
        float w2 = (tx + 128 < 200) ? wr[tx + 128]  : 0.f;
        float w3 = (tx + 192 < 200) ? wr[tx + 192]  : 0.f;
        #pragma unroll
        for (int k = 0; k < 11; ++k) {
            int t = ty + 4 * k;
            if (t < 41) {
                float a = sval[t * 256 + dd];
                acc[k][0] = fmaf(a, w0, acc[k][0]);
                acc[k][1] = fmaf(a, w1, acc[k][1]);
                acc[k][2] = fmaf(a, w2, acc[k][2]);
                acc[k][3] = fmaf(a, w3, acc[k][3]);
            }
        }
    }
    #pragma unroll
    for (int k = 0; k < 11; ++k) {
        int t = ty + 4 * k;
        float s = 0.f;
        if (t < 41) {
            if (tx < 200)       s += tanhf(acc[k][0] + bk[tx])       * qw[tx];
            if (tx + 64 < 200)  s += tanhf(acc[k][1] + bk[tx + 64])  * qw[tx + 64];
            if (tx + 128 < 200) s += tanhf(acc[k][2] + bk[tx + 128]) * qw[tx + 128];
            if (tx + 192 < 200) s += tanhf(acc[k][3] + bk[tx + 192]) * qw[tx + 192];
        }
        #pragma unroll
        for (int off = 32; off > 0; off >>= 1) s += __shfl_down(s, off, 64);
        if (tx == 0 && t < 41) skq[t] = s;
    }
    __syncthreads();
    if (tid < 64) {
        float v = (tid < 41) ? skq[tid] * SCALE_C : -1e30f;
        float m = v;
        #pragma unroll
        for (int off = 32; off > 0; off >>= 1) m = fmaxf(m, __shfl_xor(m, off, 64));
        float e = (tid < 41) ? __expf(v - m) : 0.f;
        float sum = e;
        #pragma unroll
        for (int off = 32; off > 0; off >>= 1) sum += __shfl_xor(sum, off, 64);
        if (tid < 41) skq[tid] = e / sum;
    }
    __syncthreads();
    {
        float r = 0.f;
        for (int t = 0; t < 41; ++t) r = fmaf(skq[t], sval[t * 256 + tid], r);
        g_buf[OFF_REP + (long)p * 256 + tid] = r;
    }
}

// -------- final: mean over HIS, .Wl + bl, log_softmax over CDD --------
__global__ __launch_bounds__(256) void k_final(const float* __restrict__ Wl,
                                               const float* __restrict__ bl,
                                               float* __restrict__ out)
{
    const int b = blockIdx.x, tid = threadIdx.x;
    __shared__ float ssum[4];
    __shared__ float sc5[5];
    float wl = Wl[tid];
    for (int c = 0; c < 5; ++c) {
        float fv = 0.f;
        const long base = OFF_REP + ((long)(b * 5 + c) * 50) * 256 + tid;
        for (int h = 0; h < 50; ++h) fv += g_buf[base + (long)h * 256];
        float v = fv * (1.0f / 50.0f) * wl;
        #pragma unroll
        for (int off = 32; off > 0; off >>= 1) v += __shfl_down(v, off, 64);
        if ((tid & 63) == 0) ssum[tid >> 6] = v;
        __syncthreads();
        if (tid == 0) sc5[c] = ssum[0] + ssum[1] + ssum[2] + ssum[3] + bl[0];
        __syncthreads();
    }
    if (tid == 0) {
        float m = -1e30f;
        for (int c = 0; c < 5; ++c) m = fmaxf(m, sc5[c]);
        float sum = 0.f;
        for (int c = 0; c < 5; ++c) sum += expf(sc5[c] - m);
        float lse = m + logf(sum);
        for (int c = 0; c < 5; ++c) out[b * 5 + c] = sc5[c] - lse;
    }
}

extern "C" void kernel_launch(void* const* d_in, const int* in_sizes, int n_in,
                              void* d_out, int out_size, void* d_ws, size_t ws_size,
                              hipStream_t stream)
{
    (void)in_sizes; (void)n_in; (void)d_ws; (void)ws_size; (void)out_size;
    const int*   cand  = (const int*)d_in[0];
    const int*   clk   = (const int*)d_in[1];
    const float* emb   = (const float*)d_in[2];
    const float* convw = (const float*)d_in[3];
    const float* convb = (const float*)d_in[4];
    const float* Wq    = (const float*)d_in[5];
    const float* bq    = (const float*)d_in[6];
    const float* Wv    = (const float*)d_in[7];
    const float* bv    = (const float*)d_in[8];
    const float* Wk    = (const float*)d_in[9];
    const float* bk    = (const float*)d_in[10];
    const float* qw    = (const float*)d_in[11];
    const float* Wl    = (const float*)d_in[12];
    const float* bl    = (const float*)d_in[13];
    float* out = (float*)d_out;

    k_wvr <<<256, 256, 0, stream>>>(Wv);
    k_conv<<<1280, 256, 0, stream>>>(cand, clk, emb, convw, convb);

    // bf16 conversions for the MFMA path (needs XH/XM from k_conv)
    k_cvt<<<24128, 256, 0, stream>>>(Wq);
    // QS[head] = XS @ Wq[head] + bq   (MFMA, M=20032 N=256 K=256 x16 heads)
    k_qs<<<dim3(313, 4, 16), 256, 0, stream>>>(bq);
    // SHX = Q25 @ X25^T per (bh, head)  (MFMA)
    k_gram<<<800, 256, 0, stream>>>();

    // projections (K=256 f32 GEMMs)
    gemm_k256<false><<<dim3(25, 4, 16), 256, 0, stream>>>(
        OFF_XC, 0, 0,  Wq, 0, 65536, 0,  bq, 0, 1, 256, 0,  OFF_QC, 409600, 256, 1600, 256);
    gemm_k256<true ><<<dim3(25, 4, 16), 256, 0, stream>>>(
        OFF_XC, 0, 0,  Wq, 0, 65536, 0,  nullptr, 0, 0, 0, 0,  OFF_QC2, 409600, 256, 1600, 256);
    gemm_k256<false><<<dim3(63, 4, 16), 256, 0, stream>>>(
        OFF_XM, 0, 0,  Wq, 0, 65536, 0,  bq, 0, 1, 256, 0,  OFF_QM, 1024000, 256, 4000, 256);
    gemm_k256<false><<<dim3(25, 4, 1), 256, 0, stream>>>(
        OFF_XC, 0, 0,  nullptr, OFF_WVR, 0, 0,  bv, 0, 1, 0, 0,  OFF_XVC, 0, 256, 1600, 256);
    gemm_k256<false><<<dim3(250, 4, 1), 256, 0, stream>>>(
        OFF_XH, 0, 0,  nullptr, OFF_WVR, 0, 0,  bv, 0, 1, 0, 0,  OFF_XVH, 0, 256, 16000, 256);
    gemm_k256<false><<<dim3(63, 4, 1), 256, 0, stream>>>(
        OFF_XM, 0, 0,  nullptr, OFF_WVR, 0, 0,  bv, 0, 1, 0, 0,  OFF_XVM, 0, 256, 4000, 256);
    k_bq<<<100, 256, 0, stream>>>(bq);

    // score blocks (NT f32 GEMMs)
    gemm_k256<true><<<dim3(2, 2, 256), 256, 0, stream>>>(
        OFF_QC, 409600, 25600,  nullptr, OFF_XC, 0, 25600,  nullptr, 0, 0, 0, 0,
        OFF_SCC, 10000, 100, 100, 100);
    gemm_k256<true><<<dim3(2, 16, 256), 256, 0, stream>>>(
        OFF_QC, 409600, 25600,  nullptr, OFF_XH, 0, 256000,  nullptr, 0, 0, 0, 0,
        OFF_CR1, 100000, 1000, 100, 1000);
    gemm_k256<true><<<dim3(16, 2, 256), 256, 0, stream>>>(
        OFF_XH, 0, 256000,  nullptr, OFF_QC2, 409600, 25600,  nullptr, OFF_BQC, 2, 1600, 100,
        OFF_CR2, 100000, 100, 1000, 100);
    gemm_k256<true><<<dim3(1, 1, 1280), 256, 0, stream>>>(
        OFF_QM, 1024000, 12800,  nullptr, OFF_XC, 0, 5120,  nullptr, 0, 0, 0, 0,
        OFF_SRC, 1000, 20, 50, 20);
    gemm_k256<true><<<dim3(1, 1, 1280), 256, 0, stream>>>(
        OFF_QC, 409600, 5120,  nullptr, OFF_XM, 0, 12800,  nullptr, 0, 0, 0, 0,
        OFF_SCX, 1000, 50, 20, 50);

    k_attn <<<4000, 256, 0, stream>>>();
    k_wa   <<<4000, 256, 0, stream>>>(Wk, bk, qw);
    k_final<<<16, 256, 0, stream>>>(Wl, bl, out);
}

// Round 5
// 1928.667 us; speedup vs baseline: 1.6461x; 1.2744x over previous
//
#include <hip/hip_runtime.h>
#include <hip/hip_bf16.h>
#include <math.h>

// ---------------------------------------------------------------------------
// GCAModel forward, decomposed:
//   B=16 CDD=5 HIS=50 S=20 T=41 E=300 F=256 H=16 DV=16 QD=200
//   fusion = [cdd(0..19) | SEP@20 | his(21..40)]
// Sharing exploited:
//   XC [80][20][256]  : conv out t=0..19 (cdd-only, per (b,c))
//   XH [800][20][256] : conv out t=21..40 (his-only, per (b,h))
//   XM [4000][256]    : conv out t=20 (mixed, per pair)
//   QC  = XC @ Wq[h] + bq ; QC2 = XC @ Wq[h]^T ; QM = XM @ Wq[h] + bq
//   BQC[h][m] = bq[h].XC[m]
//   score blocks: SCC = QC.XC^T, CR1 = QC.XH^T, CR2 = XH.QC2^T + BQC,
//     SRC = QM.XC^T, SCX = QC.XM^T,
//     SHX[bh][h][25][25] = (X25@Wq+bq).X25^T  (bf16 MFMA path)
//   xv = x @ Wv_r + bv ; VAL = P @ xv (bf16 out) ;
//   word-attn (NEW): kq = [tanh(VAL@Wk+bk)]@qw via MFMA (k_kq, fused epilogue),
//     then per-pair softmax + REP = w^T VAL (k_rep);
//   mean/LTR/log_softmax.
// ---------------------------------------------------------------------------

#define SCALE_C 0.05773502691896258f   // 1/sqrt(300)

typedef __attribute__((ext_vector_type(4))) float f32x4;
typedef __attribute__((ext_vector_type(8))) short short8;

static __device__ __forceinline__ unsigned short f2bf(float f)
{
    unsigned int u = __builtin_bit_cast(unsigned int, f);
    u = (u + 0x7fffu + ((u >> 16) & 1u)) >> 16;
    return (unsigned short)u;
}
static __device__ __forceinline__ float bf2f(unsigned short us)
{
    return __builtin_bit_cast(float, ((unsigned int)us) << 16);
}

// -------- static workspace (floats) --------
static constexpr long OFF_XC   = 0L;          // 80*20*256      = 409600
static constexpr long OFF_XH   = 409600L;     // 800*20*256     = 4096000
static constexpr long OFF_XM   = 4505600L;    // 4000*256       = 1024000
static constexpr long OFF_QC   = 5529600L;    // 16*1600*256    = 6553600
static constexpr long OFF_QC2  = 12083200L;   // 16*1600*256    = 6553600
static constexpr long OFF_QM   = 18636800L;   // 16*4000*256    = 16384000
static constexpr long OFF_BQC  = 35020800L;   // 16*1600        = 25600
static constexpr long OFF_WVR  = 35046400L;   // 256*256        = 65536
static constexpr long OFF_XVC  = 35111936L;   // 1600*256       = 409600
static constexpr long OFF_XVH  = 35521536L;   // 16000*256      = 4096000
static constexpr long OFF_XVM  = 39617536L;   // 4000*256       = 1024000
static constexpr long OFF_SCC  = 40641536L;   // 256*100*100    = 2560000
static constexpr long OFF_CR1  = 43201536L;   // 256*100*1000   = 25600000
static constexpr long OFF_CR2  = 68801536L;   // 256*1000*100   = 25600000
static constexpr long OFF_SRC  = 94401536L;   // 1280*50*20     = 1280000
static constexpr long OFF_SCX  = 95681536L;   // 1280*20*50     = 1280000
static constexpr long OFF_SHX  = 96961536L;   // 12800*625      = 8000000
static constexpr long OFF_REP  = 146945536L;  // 4000*256       = 1024000
static constexpr long TOTAL_F  = 147969536L;  // ~592 MB

__device__ __align__(16) float g_buf[TOTAL_F];

// bf16 side buffers for the MFMA paths
__device__ __align__(16) unsigned short g_xs[20032L * 256];        // 10.3 MB
__device__ __align__(16) unsigned short g_wqt[16L * 256 * 256];    // WqT[h][n][k]
__device__ __align__(16) unsigned short g_qs[16L * 20032 * 256];   // 164 MB
__device__ __align__(16) unsigned short g_valb[164032L * 256];     // VAL bf16, 84 MB
__device__ __align__(16) unsigned short g_wkt[208L * 256];         // WkT[n][k] (pad n>=200: 0)
__device__ __align__(16) float g_kq[164032L];                      // word-attn logits

// -------- Wv rearrange: WVR[g][h*16+d] = Wv[h][g][d] --------
__global__ __launch_bounds__(256) void k_wvr(const float* __restrict__ Wv)
{
    int i = blockIdx.x * 256 + threadIdx.x;      // 65536
    int g = i >> 8, n = i & 255;
    int h = n >> 4, d = n & 15;
    g_buf[OFF_WVR + i] = Wv[((long)h * 256 + g) * 16 + d];
}

// -------- conv (k=3, SAME, relu).  types: A=cdd rows, B=his rows, C=mixed row 20
__global__ __launch_bounds__(256) void k_conv(const int* __restrict__ cand,
                                              const int* __restrict__ clk,
                                              const float* __restrict__ emb,
                                              const float* __restrict__ W,
                                              const float* __restrict__ cbias)
{
    __shared__ float se[22][300];
    const int bid = blockIdx.x, tid = threadIdx.x;
    int type, nrows, nctx;
    int b = 0, bc = 0, bh = 0, h0 = 0;
    if (bid < 80)       { type = 0; bc = bid;      b = bc / 5; nrows = 20; nctx = 22; }
    else if (bid < 880) { type = 1; bh = bid - 80;             nrows = 20; nctx = 22; }
    else { type = 2; int g = bid - 880; bc = g / 5; h0 = (g % 5) * 10; b = bc / 5; nrows = 10; nctx = 12; }

    for (int f = tid; f < nctx * 300; f += 256) {
        int r = f / 300, e = f - r * 300;
        int tok;
        if (type == 0)      tok = (r < 20) ? cand[bc * 20 + r] : (r == 20 ? 1 : -1);
        else if (type == 1) tok = (r == 0) ? 1 : (r <= 20 ? clk[bh * 20 + r - 1] : -1);
        else                tok = (r == 0) ? cand[bc * 20 + 19] : (r == 1 ? 1 : clk[((b * 50) + h0 + (r - 2)) * 20]);
        se[r][e] = (tok < 0) ? 0.0f : emb[(long)tok * 300 + e];
    }
    __syncthreads();

    const int lane = tid & 63, w = tid >> 6;
    int co[5][3];
    #pragma unroll
    for (int q = 0; q < 5; ++q) {
        int r = w + 4 * q; int rr = (r < nrows) ? r : 0;
        #pragma unroll
        for (int dt = 0; dt < 3; ++dt) {
            int idx;
            if (type == 0)      idx = (rr + dt == 0) ? 21 : rr + dt - 1;
            else if (type == 1) idx = rr + dt;
            else                idx = (dt == 0) ? 0 : (dt == 1 ? 1 : 2 + rr);
            co[q][dt] = idx;
        }
    }
    float acc[5][4] = {};
    for (int dt = 0; dt < 3; ++dt) {
        const float* wb = W + (long)(dt * 300) * 256 + lane * 4;
        for (int e = 0; e < 300; ++e) {
            float4 w4 = *(const float4*)(wb + (long)e * 256);
            #pragma unroll
            for (int q = 0; q < 5; ++q) {
                float a = se[co[q][dt]][e];
                acc[q][0] = fmaf(a, w4.x, acc[q][0]);
                acc[q][1] = fmaf(a, w4.y, acc[q][1]);
                acc[q][2] = fmaf(a, w4.z, acc[q][2]);
                acc[q][3] = fmaf(a, w4.w, acc[q][3]);
            }
        }
    }
    float4 b4 = *(const float4*)&cbias[lane * 4];
    #pragma unroll
    for (int q = 0; q < 5; ++q) {
        int r = w + 4 * q;
        if (r < nrows) {
            float4 o;
            o.x = fmaxf(acc[q][0] + b4.x, 0.f);
            o.y = fmaxf(acc[q][1] + b4.y, 0.f);
            o.z = fmaxf(acc[q][2] + b4.z, 0.f);
            o.w = fmaxf(acc[q][3] + b4.w, 0.f);
            long row;
            if (type == 0)      row = OFF_XC + ((long)bc * 20 + r) * 256;
            else if (type == 1) row = OFF_XH + ((long)bh * 20 + r) * 256;
            else                row = OFF_XM + ((long)(bc * 50 + h0 + r)) * 256;
            *(float4*)&g_buf[row + lane * 4] = o;
        }
    }
}

// -------- generic K=256 GEMM, C = A @ B (+colbias), TB: C = A @ B^T --------
template<bool TB>
__global__ __launch_bounds__(256) void gemm_k256(
    long aOff, long aZH, long aZB,
    const float* Bext, long bOff, long bZH, long bZB,
    const float* biasExt, long biasOff, int biasKind, long sZH, long sZB,
    long cOff, long cZ, int ldc, int M, int N)
{
    const int z = blockIdx.z, head = z & 15, zo = z >> 4;
    const float* A = g_buf + aOff + (long)head * aZH + (long)zo * aZB;
    const float* B = (Bext ? Bext : (const float*)(g_buf + bOff)) + (long)head * bZH + (long)zo * bZB;
    const float* bias = nullptr;
    if (biasKind == 1)      bias = biasExt + (long)head * sZH + (long)zo * sZB;
    else if (biasKind == 2) bias = g_buf + biasOff + (long)head * sZH + (long)zo * sZB;
    float* C = g_buf + cOff + (long)z * cZ;

    const int m0 = blockIdx.x << 6, n0 = blockIdx.y << 6;
    __shared__ __align__(16) float As[32][68];
    __shared__ __align__(16) float Bs[32][68];
    const int tid = threadIdx.x;
    const int tx = tid & 15, ty = tid >> 4;
    float acc[4][4] = {};

    for (int kk = 0; kk < 256; kk += 32) {
        {   // stage A transposed: As[k][m]
            int m = tid >> 2, ks = (tid & 3) << 3;
            int row = m0 + m; if (row > M - 1) row = M - 1;
            const float* ap = A + (long)row * 256 + kk + ks;
            float4 v0 = *(const float4*)ap;
            float4 v1 = *(const float4*)(ap + 4);
            As[ks + 0][m] = v0.x; As[ks + 1][m] = v0.y; As[ks + 2][m] = v0.z; As[ks + 3][m] = v0.w;
            As[ks + 4][m] = v1.x; As[ks + 5][m] = v1.y; As[ks + 6][m] = v1.z; As[ks + 7][m] = v1.w;
        }
        if (TB) {
            int n = tid >> 2, ks = (tid & 3) << 3;
            int col = n0 + n; if (col > N - 1) col = N - 1;
            const float* bp = B + (long)col * 256 + kk + ks;
            float4 v0 = *(const float4*)bp;
            float4 v1 = *(const float4*)(bp + 4);
            Bs[ks + 0][n] = v0.x; Bs[ks + 1][n] = v0.y; Bs[ks + 2][n] = v0.z; Bs[ks + 3][n] = v0.w;
            Bs[ks + 4][n] = v1.x; Bs[ks + 5][n] = v1.y; Bs[ks + 6][n] = v1.z; Bs[ks + 7][n] = v1.w;
        } else {
            int k = tid >> 3, ns = (tid & 7) << 3;
            const float* bp = B + (long)(kk + k) * 256 + n0 + ns;
            float4 v0 = *(const float4*)bp;
            float4 v1 = *(const float4*)(bp + 4);
            float* d = &Bs[k][ns];
            d[0] = v0.x; d[1] = v0.y; d[2] = v0.z; d[3] = v0.w;
            d[4] = v1.x; d[5] = v1.y; d[6] = v1.z; d[7] = v1.w;
        }
        __syncthreads();
        #pragma unroll
        for (int k = 0; k < 32; ++k) {
            float4 a4 = *(const float4*)&As[k][ty << 2];
            float4 b4 = *(const float4*)&Bs[k][tx << 2];
            float av[4] = {a4.x, a4.y, a4.z, a4.w};
            float bv_[4] = {b4.x, b4.y, b4.z, b4.w};
            #pragma unroll
            for (int i = 0; i < 4; ++i)
                #pragma unroll
                for (int j = 0; j < 4; ++j)
                    acc[i][j] = fmaf(av[i], bv_[j], acc[i][j]);
        }
        __syncthreads();
    }
    float cb[4] = {0.f, 0.f, 0.f, 0.f};
    if (bias) {
        #pragma unroll
        for (int j = 0; j < 4; ++j) { int col = n0 + (tx << 2) + j; if (col < N) cb[j] = bias[col]; }
    }
    #pragma unroll
    for (int i = 0; i < 4; ++i) {
        int row = m0 + (ty << 2) + i;
        if (row < M) {
            #pragma unroll
            for (int j = 0; j < 4; ++j) {
                int col = n0 + (tx << 2) + j;
                if (col < N) C[(long)row * ldc + col] = acc[i][j] + cb[j];
            }
        }
    }
}

// -------- BQC[h][m] = bq[h] . XC[m] --------
__global__ __launch_bounds__(256) void k_bq(const float* __restrict__ bq)
{
    __shared__ float sbq[16][260];
    const int tid = threadIdx.x;
    for (int i = tid; i < 4096; i += 256) sbq[i >> 8][i & 255] = bq[i];
    __syncthreads();
    const int mm = tid >> 4, hh = tid & 15;
    const int m = blockIdx.x * 16 + mm;
    const float* x = &g_buf[OFF_XC + (long)m * 256];
    float s = 0.f;
    for (int g = 0; g < 256; g += 4) {
        float4 xv = *(const float4*)&x[g];
        s = fmaf(sbq[hh][g], xv.x, s);
        s = fmaf(sbq[hh][g + 1], xv.y, s);
        s = fmaf(sbq[hh][g + 2], xv.z, s);
        s = fmaf(sbq[hh][g + 3], xv.w, s);
    }
    g_buf[OFF_BQC + (long)hh * 1600 + m] = s;
}

// -------- bf16 conversion: XS (stacked X25 per bh) + WqT + WkT --------
__global__ __launch_bounds__(256) void k_cvt(const float* __restrict__ Wq,
                                             const float* __restrict__ Wk)
{
    long i = (long)blockIdx.x * 256 + threadIdx.x;
    if (i < 5120000L) {                      // XS main: 800*25*256
        int bh = (int)(i / 6400);
        int rem = (int)(i - (long)bh * 6400);
        int r = rem >> 8, e = rem & 255;
        float v;
        if (r < 20) v = g_buf[OFF_XH + ((long)bh * 20 + r) * 256 + e];
        else {
            int b = bh / 50, h = bh % 50;
            v = g_buf[OFF_XM + ((long)((b * 5 + (r - 20)) * 50 + h)) * 256 + e];
        }
        g_xs[i] = f2bf(v);
    } else if (i < 5128192L) {               // pad rows 20000..20031
        g_xs[i] = 0;
    } else if (i < 6176768L) {               // WqT[h][n][k] = Wq[h][k][n]
        long j = i - 5128192L;
        int h = (int)(j >> 16);
        int rem = (int)(j & 65535);
        int n = rem >> 8, k = rem & 255;
        g_wqt[j] = f2bf(Wq[(long)h * 65536 + k * 256 + n]);
    } else if (i < 6230016L) {               // WkT[n][k] = Wk[k][n], n>=200 -> 0
        long j = i - 6176768L;
        int n = (int)(j >> 8), k = (int)(j & 255);
        g_wkt[j] = (n < 200) ? f2bf(Wk[(long)k * 200 + n]) : 0;
    }
}

// -------- MFMA batched GEMM: QS[head] = XS @ Wq[head] + bq (bf16 in/out) ----
__global__ __launch_bounds__(256) void k_qs(const float* __restrict__ bq)
{
    const int head = blockIdx.z;
    const int m0 = blockIdx.x << 6, n0 = blockIdx.y << 6;
    __shared__ __align__(16) unsigned short Al[64][32];
    __shared__ __align__(16) unsigned short Bl[64][32];
    const int tid = threadIdx.x;
    const int lrow = tid >> 2, lch = (tid & 3) << 3;
    const unsigned short* Ag = g_xs + (long)(m0 + lrow) * 256 + lch;
    const unsigned short* Bg = g_wqt + (long)head * 65536 + (long)(n0 + lrow) * 256 + lch;
    const int w = tid >> 6, lane = tid & 63;
    const int wm = w >> 1, wn = w & 1;
    const int r16 = lane & 15, ko = lane >> 4;

    f32x4 acc00 = {0.f, 0.f, 0.f, 0.f};
    f32x4 acc01 = {0.f, 0.f, 0.f, 0.f};
    f32x4 acc10 = {0.f, 0.f, 0.f, 0.f};
    f32x4 acc11 = {0.f, 0.f, 0.f, 0.f};

    for (int kk = 0; kk < 256; kk += 32) {
        uint4 a = *(const uint4*)(Ag + kk);
        uint4 b = *(const uint4*)(Bg + kk);
        __syncthreads();
        *(uint4*)&Al[lrow][lch] = a;
        *(uint4*)&Bl[lrow][lch] = b;
        __syncthreads();
        short8 av0 = *(const short8*)&Al[wm * 32 + r16][ko * 8];
        short8 av1 = *(const short8*)&Al[wm * 32 + 16 + r16][ko * 8];
        short8 bv0 = *(const short8*)&Bl[wn * 32 + r16][ko * 8];
        short8 bv1 = *(const short8*)&Bl[wn * 32 + 16 + r16][ko * 8];
        acc00 = __builtin_amdgcn_mfma_f32_16x16x32_bf16(av0, bv0, acc00, 0, 0, 0);
        acc01 = __builtin_amdgcn_mfma_f32_16x16x32_bf16(av0, bv1, acc01, 0, 0, 0);
        acc10 = __builtin_amdgcn_mfma_f32_16x16x32_bf16(av1, bv0, acc10, 0, 0, 0);
        acc11 = __builtin_amdgcn_mfma_f32_16x16x32_bf16(av1, bv1, acc11, 0, 0, 0);
    }
    const int n_0 = n0 + wn * 32 + r16;
    const int n_1 = n_0 + 16;
    const float bb0 = bq[head * 256 + n_0];
    const float bb1 = bq[head * 256 + n_1];
    const long qbase = (long)head * 5128192L;
    const int mA = m0 + wm * 32 + ko * 4;
    const int mB = mA + 16;
    #pragma unroll
    for (int reg = 0; reg < 4; ++reg) {
        g_qs[qbase + (long)(mA + reg) * 256 + n_0] = f2bf(acc00[reg] + bb0);
        g_qs[qbase + (long)(mA + reg) * 256 + n_1] = f2bf(acc01[reg] + bb1);
        g_qs[qbase + (long)(mB + reg) * 256 + n_0] = f2bf(acc10[reg] + bb0);
        g_qs[qbase + (long)(mB + reg) * 256 + n_1] = f2bf(acc11[reg] + bb1);
    }
}

// -------- MFMA Gram per bh: SHX[bh][head] = Q25 @ X25^T --------
__global__ __launch_bounds__(256) void k_gram()
{
    const int bh = blockIdx.x;
    __shared__ __align__(16) unsigned short Xl[25][264];
    __shared__ __align__(16) unsigned short Ql[25][264];
    const int tid = threadIdx.x;
    for (int i = tid; i < 800; i += 256) {
        int row = i >> 5, c = (i & 31) << 3;
        *(uint4*)&Xl[row][c] = *(const uint4*)(g_xs + ((long)bh * 25 + row) * 256 + c);
    }
    const int w = tid >> 6, lane = tid & 63;
    const int mt = w >> 1, nt = w & 1;
    const int r16 = lane & 15, ko = lane >> 4;
    int ia = mt * 16 + r16; if (ia > 24) ia = 24;
    int jb = nt * 16 + r16; if (jb > 24) jb = 24;
    const int j = nt * 16 + r16;

    for (int head = 0; head < 16; ++head) {
        __syncthreads();
        for (int i = tid; i < 800; i += 256) {
            int row = i >> 5, c = (i & 31) << 3;
            *(uint4*)&Ql[row][c] =
                *(const uint4*)(g_qs + (long)head * 5128192L + ((long)bh * 25 + row) * 256 + c);
        }
        __syncthreads();
        f32x4 acc = {0.f, 0.f, 0.f, 0.f};
        #pragma unroll
        for (int k0 = 0; k0 < 256; k0 += 32) {
            short8 av = *(const short8*)&Ql[ia][k0 + ko * 8];
            short8 bv = *(const short8*)&Xl[jb][k0 + ko * 8];
            acc = __builtin_amdgcn_mfma_f32_16x16x32_bf16(av, bv, acc, 0, 0, 0);
        }
        if (j < 25) {
            #pragma unroll
            for (int reg = 0; reg < 4; ++reg) {
                int i2 = mt * 16 + ko * 4 + reg;
                if (i2 < 25)
                    g_buf[OFF_SHX + ((long)bh * 16 + head) * 625 + i2 * 25 + j] = acc[reg];
            }
        }
    }
}

// -------- per-pair attention: assemble scores (pure loads), softmax, P@xv ----
// writes VAL in bf16 (g_valb)
__global__ __launch_bounds__(256) void k_attn()
{
    const int p = blockIdx.x;
    const int b = p / 250;
    const int c = (p / 50) % 5;
    const int h = p % 50;
    const int bc = b * 5 + c;
    const int bh = b * 50 + h;
    __shared__ float ssc[41][44];
    __shared__ float sxv[41][16];
    const int tid = threadIdx.x;
    for (int head = 0; head < 16; ++head) {
        const long z  = b * 16 + head;
        const long zc = bc * 16 + head;
        const long zh = (long)bh * 16 + head;
        for (int i = tid; i < 41 * 16; i += 256) {
            int r = i >> 4, d = i & 15;
            float v;
            if (r < 20)       v = g_buf[OFF_XVC + ((long)bc * 20 + r) * 256 + head * 16 + d];
            else if (r == 20) v = g_buf[OFF_XVM + (long)p * 256 + head * 16 + d];
            else              v = g_buf[OFF_XVH + ((long)bh * 20 + (r - 21)) * 256 + head * 16 + d];
            sxv[r][d] = v;
        }
        for (int i = tid; i < 1681; i += 256) {
            int t = i / 41, s = i - t * 41;
            float v;
            if (t < 20) {
                if (s < 20)       v = g_buf[OFF_SCC + z * 10000 + (c * 20 + t) * 100 + (c * 20 + s)];
                else if (s == 20) v = g_buf[OFF_SCX + zc * 1000 + t * 50 + h];
                else              v = g_buf[OFF_CR1 + z * 100000 + (long)(c * 20 + t) * 1000 + h * 20 + (s - 21)];
            } else if (t == 20) {
                if (s < 20)       v = g_buf[OFF_SRC + zc * 1000 + h * 20 + s];
                else              v = g_buf[OFF_SHX + zh * 625 + (20 + c) * 25 + ((s == 20) ? (20 + c) : (s - 21))];
            } else {
                if (s < 20)       v = g_buf[OFF_CR2 + z * 100000 + (long)(h * 20 + (t - 21)) * 100 + (c * 20 + s)];
                else              v = g_buf[OFF_SHX + zh * 625 + (t - 21) * 25 + ((s == 20) ? (20 + c) : (s - 21))];
            }
            ssc[t][s] = v * SCALE_C;
        }
        __syncthreads();
        if (tid < 41) {
            float m = -1e30f;
            for (int s2 = 0; s2 < 41; ++s2) m = fmaxf(m, ssc[tid][s2]);
            float sum = 0.f;
            for (int s2 = 0; s2 < 41; ++s2) { float e = __expf(ssc[tid][s2] - m); ssc[tid][s2] = e; sum += e; }
            float inv = 1.f / sum;
            for (int s2 = 0; s2 < 41; ++s2) ssc[tid][s2] *= inv;
        }
        __syncthreads();
        {
            const int t0 = tid >> 4, d = tid & 15;
            for (int t = t0; t < 41; t += 16) {
                float a = 0.f;
                for (int s2 = 0; s2 < 41; ++s2) a = fmaf(ssc[t][s2], sxv[s2][d], a);
                g_valb[((long)p * 41 + t) * 256 + head * 16 + d] = f2bf(a);
            }
        }
        __syncthreads();
    }
}

// -------- word-attn logits via MFMA: kq[m] = sum_n tanh(VAL[m]@WkT[n]+bk[n])*qw[n]
// 64 rows/block, 4 waves: wave w owns rows w*16..w*16+15, all 13 n-tiles (N=208 padded).
__global__ __launch_bounds__(256) void k_kq(const float* __restrict__ bk,
                                            const float* __restrict__ qw)
{
    const int blk = blockIdx.x;
    const long m0 = (long)blk * 64;
    __shared__ __align__(16) unsigned short sA[64][264];   // +8 pad: 2-way max
    __shared__ __align__(16) unsigned short sWk[208][40];  // +8 pad: conflict-free
    const int tid = threadIdx.x;

    // stage A rows (row-clamped)
    for (int i = tid; i < 2048; i += 256) {
        int rloc = i >> 5, cg = (i & 31) << 3;
        long grow = m0 + rloc; if (grow > 163999L) grow = 163999L;
        *(uint4*)&sA[rloc][cg] = *(const uint4*)(g_valb + grow * 256 + cg);
    }

    const int w = tid >> 6, lane = tid & 63;
    const int r16 = lane & 15, ko = lane >> 4;

    f32x4 acc[13];
    #pragma unroll
    for (int j = 0; j < 13; ++j) acc[j] = (f32x4){0.f, 0.f, 0.f, 0.f};

    for (int kk = 0; kk < 8; ++kk) {
        __syncthreads();
        for (int i = tid; i < 832; i += 256) {
            int n = i >> 2, cg = (i & 3) << 3;
            *(uint4*)&sWk[n][cg] = *(const uint4*)(g_wkt + (long)n * 256 + kk * 32 + cg);
        }
        __syncthreads();
        short8 av = *(const short8*)&sA[w * 16 + r16][kk * 32 + ko * 8];
        #pragma unroll
        for (int j = 0; j < 13; ++j) {
            short8 bv = *(const short8*)&sWk[j * 16 + r16][ko * 8];
            acc[j] = __builtin_amdgcn_mfma_f32_16x16x32_bf16(av, bv, acc[j], 0, 0, 0);
        }
    }

    // epilogue: s[reg] = sum_j tanh(acc + bk)*qw over this lane's column,
    // then reduce across the 16 lanes (cols) of each lane-group.
    float s0 = 0.f, s1 = 0.f, s2 = 0.f, s3 = 0.f;
    #pragma unroll
    for (int j = 0; j < 13; ++j) {
        int cj = j * 16 + r16;
        float bkv = (cj < 200) ? bk[cj] : 0.f;
        float qwv = (cj < 200) ? qw[cj] : 0.f;
        s0 = fmaf(tanhf(acc[j][0] + bkv), qwv, s0);
        s1 = fmaf(tanhf(acc[j][1] + bkv), qwv, s1);
        s2 = fmaf(tanhf(acc[j][2] + bkv), qwv, s2);
        s3 = fmaf(tanhf(acc[j][3] + bkv), qwv, s3);
    }
    #pragma unroll
    for (int off = 1; off < 16; off <<= 1) {
        s0 += __shfl_xor(s0, off, 64);
        s1 += __shfl_xor(s1, off, 64);
        s2 += __shfl_xor(s2, off, 64);
        s3 += __shfl_xor(s3, off, 64);
    }
    if ((lane & 15) == 0) {
        long rbase = m0 + w * 16 + ko * 4;
        if (rbase + 0 < 164000L) g_kq[rbase + 0] = s0;
        if (rbase + 1 < 164000L) g_kq[rbase + 1] = s1;
        if (rbase + 2 < 164000L) g_kq[rbase + 2] = s2;
        if (rbase + 3 < 164000L) g_kq[rbase + 3] = s3;
    }
}

// -------- per-pair: softmax(kq*SCALE) over t, REP = w^T VAL --------
__global__ __launch_bounds__(256) void k_rep()
{
    const int p = blockIdx.x, tid = threadIdx.x;
    __shared__ __align__(16) unsigned short sval[41 * 256];
    __shared__ float skq[41];
    for (int i = tid; i < 1312; i += 256)
        ((uint4*)sval)[i] = ((const uint4*)(g_valb + (long)p * 41 * 256))[i];
    if (tid < 64) {
        float v = (tid < 41) ? g_kq[(long)p * 41 + tid] * SCALE_C : -1e30f;
        float m = v;
        #pragma unroll
        for (int off = 32; off > 0; off >>= 1) m = fmaxf(m, __shfl_xor(m, off, 64));
        float e = (tid < 41) ? __expf(v - m) : 0.f;
        float sum = e;
        #pragma unroll
        for (int off = 32; off > 0; off >>= 1) sum += __shfl_xor(sum, off, 64);
        if (tid < 41) skq[tid] = e / sum;
    }
    __syncthreads();
    float r = 0.f;
    for (int t = 0; t < 41; ++t) r = fmaf(skq[t], bf2f(sval[t * 256 + tid]), r);
    g_buf[OFF_REP + (long)p * 256 + tid] = r;
}

// -------- final: mean over HIS, .Wl + bl, log_softmax over CDD --------
__global__ __launch_bounds__(256) void k_final(const float* __restrict__ Wl,
                                               const float* __restrict__ bl,
                                               float* __restrict__ out)
{
    const int b = blockIdx.x, tid = threadIdx.x;
    __shared__ float ssum[4];
    __shared__ float sc5[5];
    float wl = Wl[tid];
    for (int c = 0; c < 5; ++c) {
        float fv = 0.f;
        const long base = OFF_REP + ((long)(b * 5 + c) * 50) * 256 + tid;
        for (int h = 0; h < 50; ++h) fv += g_buf[base + (long)h * 256];
        float v = fv * (1.0f / 50.0f) * wl;
        #pragma unroll
        for (int off = 32; off > 0; off >>= 1) v += __shfl_down(v, off, 64);
        if ((tid & 63) == 0) ssum[tid >> 6] = v;
        __syncthreads();
        if (tid == 0) sc5[c] = ssum[0] + ssum[1] + ssum[2] + ssum[3] + bl[0];
        __syncthreads();
    }
    if (tid == 0) {
        float m = -1e30f;
        for (int c = 0; c < 5; ++c) m = fmaxf(m, sc5[c]);
        float sum = 0.f;
        for (int c = 0; c < 5; ++c) sum += expf(sc5[c] - m);
        float lse = m + logf(sum);
        for (int c = 0; c < 5; ++c) out[b * 5 + c] = sc5[c] - lse;
    }
}

extern "C" void kernel_launch(void* const* d_in, const int* in_sizes, int n_in,
                              void* d_out, int out_size, void* d_ws, size_t ws_size,
                              hipStream_t stream)
{
    (void)in_sizes; (void)n_in; (void)d_ws; (void)ws_size; (void)out_size;
    const int*   cand  = (const int*)d_in[0];
    const int*   clk   = (const int*)d_in[1];
    const float* emb   = (const float*)d_in[2];
    const float* convw = (const float*)d_in[3];
    const float* convb = (const float*)d_in[4];
    const float* Wq    = (const float*)d_in[5];
    const float* bq    = (const float*)d_in[6];
    const float* Wv    = (const float*)d_in[7];
    const float* bv    = (const float*)d_in[8];
    const float* Wk    = (const float*)d_in[9];
    const float* bk    = (const float*)d_in[10];
    const float* qw    = (const float*)d_in[11];
    const float* Wl    = (const float*)d_in[12];
    const float* bl    = (const float*)d_in[13];
    float* out = (float*)d_out;

    k_wvr <<<256, 256, 0, stream>>>(Wv);
    k_conv<<<1280, 256, 0, stream>>>(cand, clk, emb, convw, convb);

    // bf16 conversions for the MFMA paths (needs XH/XM from k_conv)
    k_cvt<<<24336, 256, 0, stream>>>(Wq, Wk);
    // QS[head] = XS @ Wq[head] + bq   (MFMA, M=20032 N=256 K=256 x16 heads)
    k_qs<<<dim3(313, 4, 16), 256, 0, stream>>>(bq);
    // SHX = Q25 @ X25^T per (bh, head)  (MFMA)
    k_gram<<<800, 256, 0, stream>>>();

    // projections (K=256 f32 GEMMs)
    gemm_k256<false><<<dim3(25, 4, 16), 256, 0, stream>>>(
        OFF_XC, 0, 0,  Wq, 0, 65536, 0,  bq, 0, 1, 256, 0,  OFF_QC, 409600, 256, 1600, 256);
    gemm_k256<true ><<<dim3(25, 4, 16), 256, 0, stream>>>(
        OFF_XC, 0, 0,  Wq, 0, 65536, 0,  nullptr, 0, 0, 0, 0,  OFF_QC2, 409600, 256, 1600, 256);
    gemm_k256<false><<<dim3(63, 4, 16), 256, 0, stream>>>(
        OFF_XM, 0, 0,  Wq, 0, 65536, 0,  bq, 0, 1, 256, 0,  OFF_QM, 1024000, 256, 4000, 256);
    gemm_k256<false><<<dim3(25, 4, 1), 256, 0, stream>>>(
        OFF_XC, 0, 0,  nullptr, OFF_WVR, 0, 0,  bv, 0, 1, 0, 0,  OFF_XVC, 0, 256, 1600, 256);
    gemm_k256<false><<<dim3(250, 4, 1), 256, 0, stream>>>(
        OFF_XH, 0, 0,  nullptr, OFF_WVR, 0, 0,  bv, 0, 1, 0, 0,  OFF_XVH, 0, 256, 16000, 256);
    gemm_k256<false><<<dim3(63, 4, 1), 256, 0, stream>>>(
        OFF_XM, 0, 0,  nullptr, OFF_WVR, 0, 0,  bv, 0, 1, 0, 0,  OFF_XVM, 0, 256, 4000, 256);
    k_bq<<<100, 256, 0, stream>>>(bq);

    // score blocks (NT f32 GEMMs)
    gemm_k256<true><<<dim3(2, 2, 256), 256, 0, stream>>>(
        OFF_QC, 409600, 25600,  nullptr, OFF_XC, 0, 25600,  nullptr, 0, 0, 0, 0,
        OFF_SCC, 10000, 100, 100, 100);
    gemm_k256<true><<<dim3(2, 16, 256), 256, 0, stream>>>(
        OFF_QC, 409600, 25600,  nullptr, OFF_XH, 0, 256000,  nullptr, 0, 0, 0, 0,
        OFF_CR1, 100000, 1000, 100, 1000);
    gemm_k256<true><<<dim3(16, 2, 256), 256, 0, stream>>>(
        OFF_XH, 0, 256000,  nullptr, OFF_QC2, 409600, 25600,  nullptr, OFF_BQC, 2, 1600, 100,
        OFF_CR2, 100000, 100, 1000, 100);
    gemm_k256<true><<<dim3(1, 1, 1280), 256, 0, stream>>>(
        OFF_QM, 1024000, 12800,  nullptr, OFF_XC, 0, 5120,  nullptr, 0, 0, 0, 0,
        OFF_SRC, 1000, 20, 50, 20);
    gemm_k256<true><<<dim3(1, 1, 1280), 256, 0, stream>>>(
        OFF_QC, 409600, 5120,  nullptr, OFF_XM, 0, 12800,  nullptr, 0, 0, 0, 0,
        OFF_SCX, 1000, 50, 20, 50);

    k_attn<<<4000, 256, 0, stream>>>();

    // word attention: MFMA logits + per-pair softmax/REP
    k_kq <<<2563, 256, 0, stream>>>(bk, qw);
    k_rep<<<4000, 256, 0, stream>>>();

    k_final<<<16, 256, 0, stream>>>(Wl, bl, out);
}

// Round 6
// 1741.583 us; speedup vs baseline: 1.8230x; 1.1074x over previous
//
#include <hip/hip_runtime.h>
#include <hip/hip_bf16.h>
#include <math.h>

// ---------------------------------------------------------------------------
// GCAModel forward, decomposed:
//   B=16 CDD=5 HIS=50 S=20 T=41 E=300 F=256 H=16 DV=16 QD=200
//   fusion = [cdd(0..19) | SEP@20 | his(21..40)]
// Sharing exploited:
//   XC [80][20][256]  : conv out t=0..19 (cdd-only, per (b,c))
//   XH [800][20][256] : conv out t=21..40 (his-only, per (b,h))
//   XM [4000][256]    : conv out t=20 (mixed, per pair)
//   QC  = XC @ Wq[h] + bq ; QC2 = XC @ Wq[h]^T
//   BQC[h][m] = bq[h].XC[m]
//   score blocks: SCC = QC.XC^T, CR1 = QC.XH^T, CR2 = XH.QC2^T + BQC,
//     SRC from g_qs rows t=20 (k_src, MFMA), SCX = QC.XM^T,
//     SHX[bh][h][25(stride28)] = (X25@Wq+bq).X25^T  (bf16 MFMA)
//   xv = x @ Wv_r + bv ;
//   k_attn2: wave-per-head, row-in-registers softmax+PV, VAL bf16 (permuted
//     t/s order — consumers are permutation-invariant);
//   word-attn: kq = [tanh(VAL@Wk+bk)]@qw via MFMA (k_kq), softmax+REP (k_rep);
//   mean/LTR/log_softmax.
// ---------------------------------------------------------------------------

#define SCALE_C 0.05773502691896258f   // 1/sqrt(300)

typedef __attribute__((ext_vector_type(4))) float f32x4;
typedef __attribute__((ext_vector_type(8))) short short8;

static __device__ __forceinline__ unsigned short f2bf(float f)
{
    unsigned int u = __builtin_bit_cast(unsigned int, f);
    u = (u + 0x7fffu + ((u >> 16) & 1u)) >> 16;
    return (unsigned short)u;
}
static __device__ __forceinline__ float bf2f(unsigned short us)
{
    return __builtin_bit_cast(float, ((unsigned int)us) << 16);
}

// -------- static workspace (floats) --------
static constexpr long OFF_XC   = 0L;          // 80*20*256      = 409600
static constexpr long OFF_XH   = 409600L;     // 800*20*256     = 4096000
static constexpr long OFF_XM   = 4505600L;    // 4000*256       = 1024000
static constexpr long OFF_QC   = 5529600L;    // 16*1600*256    = 6553600
static constexpr long OFF_QC2  = 12083200L;   // 16*1600*256    = 6553600
static constexpr long OFF_BQC  = 35020800L;   // 16*1600        = 25600
static constexpr long OFF_WVR  = 35046400L;   // 256*256        = 65536
static constexpr long OFF_XVC  = 35111936L;   // 1600*256       = 409600
static constexpr long OFF_XVH  = 35521536L;   // 16000*256      = 4096000
static constexpr long OFF_XVM  = 39617536L;   // 4000*256       = 1024000
static constexpr long OFF_SCC  = 40641536L;   // 256*100*100    = 2560000
static constexpr long OFF_CR1  = 43201536L;   // 256*100*1000   = 25600000
static constexpr long OFF_CR2  = 68801536L;   // 256*1000*100   = 25600000
static constexpr long OFF_SRC  = 94401536L;   // 1280*50*20     = 1280000
static constexpr long OFF_SCX  = 95681536L;   // 1280*20*50     = 1280000
static constexpr long OFF_SHX  = 96961536L;   // 12800*700      = 8960000 (25 rows, stride 28)
static constexpr long OFF_REP  = 146945536L;  // 4000*256       = 1024000
static constexpr long TOTAL_F  = 147969536L;  // ~592 MB

__device__ __align__(16) float g_buf[TOTAL_F];

// bf16 side buffers for the MFMA paths
__device__ __align__(16) unsigned short g_xs[20032L * 256];        // 10.3 MB
__device__ __align__(16) unsigned short g_wqt[16L * 256 * 256];    // WqT[h][n][k]
__device__ __align__(16) unsigned short g_qs[16L * 20032 * 256];   // 164 MB
__device__ __align__(16) unsigned short g_valb[164032L * 256];     // VAL bf16, 84 MB
__device__ __align__(16) unsigned short g_wkt[208L * 256];         // WkT[n][k] (pad n>=200: 0)
__device__ __align__(16) unsigned short g_xcb[1600L * 256];        // XC bf16
__device__ __align__(16) float g_kq[164032L];                      // word-attn logits

// -------- Wv rearrange: WVR[g][h*16+d] = Wv[h][g][d] --------
__global__ __launch_bounds__(256) void k_wvr(const float* __restrict__ Wv)
{
    int i = blockIdx.x * 256 + threadIdx.x;      // 65536
    int g = i >> 8, n = i & 255;
    int h = n >> 4, d = n & 15;
    g_buf[OFF_WVR + i] = Wv[((long)h * 256 + g) * 16 + d];
}

// -------- conv (k=3, SAME, relu).  types: A=cdd rows, B=his rows, C=mixed row 20
__global__ __launch_bounds__(256) void k_conv(const int* __restrict__ cand,
                                              const int* __restrict__ clk,
                                              const float* __restrict__ emb,
                                              const float* __restrict__ W,
                                              const float* __restrict__ cbias)
{
    __shared__ float se[22][300];
    const int bid = blockIdx.x, tid = threadIdx.x;
    int type, nrows, nctx;
    int b = 0, bc = 0, bh = 0, h0 = 0;
    if (bid < 80)       { type = 0; bc = bid;      b = bc / 5; nrows = 20; nctx = 22; }
    else if (bid < 880) { type = 1; bh = bid - 80;             nrows = 20; nctx = 22; }
    else { type = 2; int g = bid - 880; bc = g / 5; h0 = (g % 5) * 10; b = bc / 5; nrows = 10; nctx = 12; }

    for (int f = tid; f < nctx * 300; f += 256) {
        int r = f / 300, e = f - r * 300;
        int tok;
        if (type == 0)      tok = (r < 20) ? cand[bc * 20 + r] : (r == 20 ? 1 : -1);
        else if (type == 1) tok = (r == 0) ? 1 : (r <= 20 ? clk[bh * 20 + r - 1] : -1);
        else                tok = (r == 0) ? cand[bc * 20 + 19] : (r == 1 ? 1 : clk[((b * 50) + h0 + (r - 2)) * 20]);
        se[r][e] = (tok < 0) ? 0.0f : emb[(long)tok * 300 + e];
    }
    __syncthreads();

    const int lane = tid & 63, w = tid >> 6;
    int co[5][3];
    #pragma unroll
    for (int q = 0; q < 5; ++q) {
        int r = w + 4 * q; int rr = (r < nrows) ? r : 0;
        #pragma unroll
        for (int dt = 0; dt < 3; ++dt) {
            int idx;
            if (type == 0)      idx = (rr + dt == 0) ? 21 : rr + dt - 1;
            else if (type == 1) idx = rr + dt;
            else                idx = (dt == 0) ? 0 : (dt == 1 ? 1 : 2 + rr);
            co[q][dt] = idx;
        }
    }
    float acc[5][4] = {};
    for (int dt = 0; dt < 3; ++dt) {
        const float* wb = W + (long)(dt * 300) * 256 + lane * 4;
        for (int e = 0; e < 300; ++e) {
            float4 w4 = *(const float4*)(wb + (long)e * 256);
            #pragma unroll
            for (int q = 0; q < 5; ++q) {
                float a = se[co[q][dt]][e];
                acc[q][0] = fmaf(a, w4.x, acc[q][0]);
                acc[q][1] = fmaf(a, w4.y, acc[q][1]);
                acc[q][2] = fmaf(a, w4.z, acc[q][2]);
                acc[q][3] = fmaf(a, w4.w, acc[q][3]);
            }
        }
    }
    float4 b4 = *(const float4*)&cbias[lane * 4];
    #pragma unroll
    for (int q = 0; q < 5; ++q) {
        int r = w + 4 * q;
        if (r < nrows) {
            float4 o;
            o.x = fmaxf(acc[q][0] + b4.x, 0.f);
            o.y = fmaxf(acc[q][1] + b4.y, 0.f);
            o.z = fmaxf(acc[q][2] + b4.z, 0.f);
            o.w = fmaxf(acc[q][3] + b4.w, 0.f);
            long row;
            if (type == 0)      row = OFF_XC + ((long)bc * 20 + r) * 256;
            else if (type == 1) row = OFF_XH + ((long)bh * 20 + r) * 256;
            else                row = OFF_XM + ((long)(bc * 50 + h0 + r)) * 256;
            *(float4*)&g_buf[row + lane * 4] = o;
        }
    }
}

// -------- generic K=256 GEMM, C = A @ B (+colbias), TB: C = A @ B^T --------
template<bool TB>
__global__ __launch_bounds__(256) void gemm_k256(
    long aOff, long aZH, long aZB,
    const float* Bext, long bOff, long bZH, long bZB,
    const float* biasExt, long biasOff, int biasKind, long sZH, long sZB,
    long cOff, long cZ, int ldc, int M, int N)
{
    const int z = blockIdx.z, head = z & 15, zo = z >> 4;
    const float* A = g_buf + aOff + (long)head * aZH + (long)zo * aZB;
    const float* B = (Bext ? Bext : (const float*)(g_buf + bOff)) + (long)head * bZH + (long)zo * bZB;
    const float* bias = nullptr;
    if (biasKind == 1)      bias = biasExt + (long)head * sZH + (long)zo * sZB;
    else if (biasKind == 2) bias = g_buf + biasOff + (long)head * sZH + (long)zo * sZB;
    float* C = g_buf + cOff + (long)z * cZ;

    const int m0 = blockIdx.x << 6, n0 = blockIdx.y << 6;
    __shared__ __align__(16) float As[32][68];
    __shared__ __align__(16) float Bs[32][68];
    const int tid = threadIdx.x;
    const int tx = tid & 15, ty = tid >> 4;
    float acc[4][4] = {};

    for (int kk = 0; kk < 256; kk += 32) {
        {   // stage A transposed: As[k][m]
            int m = tid >> 2, ks = (tid & 3) << 3;
            int row = m0 + m; if (row > M - 1) row = M - 1;
            const float* ap = A + (long)row * 256 + kk + ks;
            float4 v0 = *(const float4*)ap;
            float4 v1 = *(const float4*)(ap + 4);
            As[ks + 0][m] = v0.x; As[ks + 1][m] = v0.y; As[ks + 2][m] = v0.z; As[ks + 3][m] = v0.w;
            As[ks + 4][m] = v1.x; As[ks + 5][m] = v1.y; As[ks + 6][m] = v1.z; As[ks + 7][m] = v1.w;
        }
        if (TB) {
            int n = tid >> 2, ks = (tid & 3) << 3;
            int col = n0 + n; if (col > N - 1) col = N - 1;
            const float* bp = B + (long)col * 256 + kk + ks;
            float4 v0 = *(const float4*)bp;
            float4 v1 = *(const float4*)(bp + 4);
            Bs[ks + 0][n] = v0.x; Bs[ks + 1][n] = v0.y; Bs[ks + 2][n] = v0.z; Bs[ks + 3][n] = v0.w;
            Bs[ks + 4][n] = v1.x; Bs[ks + 5][n] = v1.y; Bs[ks + 6][n] = v1.z; Bs[ks + 7][n] = v1.w;
        } else {
            int k = tid >> 3, ns = (tid & 7) << 3;
            const float* bp = B + (long)(kk + k) * 256 + n0 + ns;
            float4 v0 = *(const float4*)bp;
            float4 v1 = *(const float4*)(bp + 4);
            float* d = &Bs[k][ns];
            d[0] = v0.x; d[1] = v0.y; d[2] = v0.z; d[3] = v0.w;
            d[4] = v1.x; d[5] = v1.y; d[6] = v1.z; d[7] = v1.w;
        }
        __syncthreads();
        #pragma unroll
        for (int k = 0; k < 32; ++k) {
            float4 a4 = *(const float4*)&As[k][ty << 2];
            float4 b4 = *(const float4*)&Bs[k][tx << 2];
            float av[4] = {a4.x, a4.y, a4.z, a4.w};
            float bv_[4] = {b4.x, b4.y, b4.z, b4.w};
            #pragma unroll
            for (int i = 0; i < 4; ++i)
                #pragma unroll
                for (int j = 0; j < 4; ++j)
                    acc[i][j] = fmaf(av[i], bv_[j], acc[i][j]);
        }
        __syncthreads();
    }
    float cb[4] = {0.f, 0.f, 0.f, 0.f};
    if (bias) {
        #pragma unroll
        for (int j = 0; j < 4; ++j) { int col = n0 + (tx << 2) + j; if (col < N) cb[j] = bias[col]; }
    }
    #pragma unroll
    for (int i = 0; i < 4; ++i) {
        int row = m0 + (ty << 2) + i;
        if (row < M) {
            #pragma unroll
            for (int j = 0; j < 4; ++j) {
                int col = n0 + (tx << 2) + j;
                if (col < N) C[(long)row * ldc + col] = acc[i][j] + cb[j];
            }
        }
    }
}

// -------- BQC[h][m] = bq[h] . XC[m] --------
__global__ __launch_bounds__(256) void k_bq(const float* __restrict__ bq)
{
    __shared__ float sbq[16][260];
    const int tid = threadIdx.x;
    for (int i = tid; i < 4096; i += 256) sbq[i >> 8][i & 255] = bq[i];
    __syncthreads();
    const int mm = tid >> 4, hh = tid & 15;
    const int m = blockIdx.x * 16 + mm;
    const float* x = &g_buf[OFF_XC + (long)m * 256];
    float s = 0.f;
    for (int g = 0; g < 256; g += 4) {
        float4 xv = *(const float4*)&x[g];
        s = fmaf(sbq[hh][g], xv.x, s);
        s = fmaf(sbq[hh][g + 1], xv.y, s);
        s = fmaf(sbq[hh][g + 2], xv.z, s);
        s = fmaf(sbq[hh][g + 3], xv.w, s);
    }
    g_buf[OFF_BQC + (long)hh * 1600 + m] = s;
}

// -------- bf16 conversion: XS + WqT + WkT + XCb --------
__global__ __launch_bounds__(256) void k_cvt(const float* __restrict__ Wq,
                                             const float* __restrict__ Wk)
{
    long i = (long)blockIdx.x * 256 + threadIdx.x;
    if (i < 5120000L) {                      // XS main: 800*25*256
        int bh = (int)(i / 6400);
        int rem = (int)(i - (long)bh * 6400);
        int r = rem >> 8, e = rem & 255;
        float v;
        if (r < 20) v = g_buf[OFF_XH + ((long)bh * 20 + r) * 256 + e];
        else {
            int b = bh / 50, h = bh % 50;
            v = g_buf[OFF_XM + ((long)((b * 5 + (r - 20)) * 50 + h)) * 256 + e];
        }
        g_xs[i] = f2bf(v);
    } else if (i < 5128192L) {               // pad rows 20000..20031
        g_xs[i] = 0;
    } else if (i < 6176768L) {               // WqT[h][n][k] = Wq[h][k][n]
        long j = i - 5128192L;
        int h = (int)(j >> 16);
        int rem = (int)(j & 65535);
        int n = rem >> 8, k = rem & 255;
        g_wqt[j] = f2bf(Wq[(long)h * 65536 + k * 256 + n]);
    } else if (i < 6230016L) {               // WkT[n][k] = Wk[k][n], n>=200 -> 0
        long j = i - 6176768L;
        int n = (int)(j >> 8), k = (int)(j & 255);
        g_wkt[j] = (n < 200) ? f2bf(Wk[(long)k * 200 + n]) : 0;
    } else if (i < 6639616L) {               // XC -> bf16
        long j = i - 6230016L;
        g_xcb[j] = f2bf(g_buf[OFF_XC + j]);
    }
}

// -------- MFMA batched GEMM: QS[head] = XS @ Wq[head] + bq (bf16 in/out) ----
__global__ __launch_bounds__(256) void k_qs(const float* __restrict__ bq)
{
    const int head = blockIdx.z;
    const int m0 = blockIdx.x << 6, n0 = blockIdx.y << 6;
    __shared__ __align__(16) unsigned short Al[64][32];
    __shared__ __align__(16) unsigned short Bl[64][32];
    const int tid = threadIdx.x;
    const int lrow = tid >> 2, lch = (tid & 3) << 3;
    const unsigned short* Ag = g_xs + (long)(m0 + lrow) * 256 + lch;
    const unsigned short* Bg = g_wqt + (long)head * 65536 + (long)(n0 + lrow) * 256 + lch;
    const int w = tid >> 6, lane = tid & 63;
    const int wm = w >> 1, wn = w & 1;
    const int r16 = lane & 15, ko = lane >> 4;

    f32x4 acc00 = {0.f, 0.f, 0.f, 0.f};
    f32x4 acc01 = {0.f, 0.f, 0.f, 0.f};
    f32x4 acc10 = {0.f, 0.f, 0.f, 0.f};
    f32x4 acc11 = {0.f, 0.f, 0.f, 0.f};

    for (int kk = 0; kk < 256; kk += 32) {
        uint4 a = *(const uint4*)(Ag + kk);
        uint4 b = *(const uint4*)(Bg + kk);
        __syncthreads();
        *(uint4*)&Al[lrow][lch] = a;
        *(uint4*)&Bl[lrow][lch] = b;
        __syncthreads();
        short8 av0 = *(const short8*)&Al[wm * 32 + r16][ko * 8];
        short8 av1 = *(const short8*)&Al[wm * 32 + 16 + r16][ko * 8];
        short8 bv0 = *(const short8*)&Bl[wn * 32 + r16][ko * 8];
        short8 bv1 = *(const short8*)&Bl[wn * 32 + 16 + r16][ko * 8];
        acc00 = __builtin_amdgcn_mfma_f32_16x16x32_bf16(av0, bv0, acc00, 0, 0, 0);
        acc01 = __builtin_amdgcn_mfma_f32_16x16x32_bf16(av0, bv1, acc01, 0, 0, 0);
        acc10 = __builtin_amdgcn_mfma_f32_16x16x32_bf16(av1, bv0, acc10, 0, 0, 0);
        acc11 = __builtin_amdgcn_mfma_f32_16x16x32_bf16(av1, bv1, acc11, 0, 0, 0);
    }
    const int n_0 = n0 + wn * 32 + r16;
    const int n_1 = n_0 + 16;
    const float bb0 = bq[head * 256 + n_0];
    const float bb1 = bq[head * 256 + n_1];
    const long qbase = (long)head * 5128192L;
    const int mA = m0 + wm * 32 + ko * 4;
    const int mB = mA + 16;
    #pragma unroll
    for (int reg = 0; reg < 4; ++reg) {
        g_qs[qbase + (long)(mA + reg) * 256 + n_0] = f2bf(acc00[reg] + bb0);
        g_qs[qbase + (long)(mA + reg) * 256 + n_1] = f2bf(acc01[reg] + bb1);
        g_qs[qbase + (long)(mB + reg) * 256 + n_0] = f2bf(acc10[reg] + bb0);
        g_qs[qbase + (long)(mB + reg) * 256 + n_1] = f2bf(acc11[reg] + bb1);
    }
}

// -------- MFMA Gram per bh: SHX[bh][head] = Q25 @ X25^T (row stride 28) ----
__global__ __launch_bounds__(256) void k_gram()
{
    const int bh = blockIdx.x;
    __shared__ __align__(16) unsigned short Xl[25][264];
    __shared__ __align__(16) unsigned short Ql[25][264];
    const int tid = threadIdx.x;
    for (int i = tid; i < 800; i += 256) {
        int row = i >> 5, c = (i & 31) << 3;
        *(uint4*)&Xl[row][c] = *(const uint4*)(g_xs + ((long)bh * 25 + row) * 256 + c);
    }
    const int w = tid >> 6, lane = tid & 63;
    const int mt = w >> 1, nt = w & 1;
    const int r16 = lane & 15, ko = lane >> 4;
    int ia = mt * 16 + r16; if (ia > 24) ia = 24;
    int jb = nt * 16 + r16; if (jb > 24) jb = 24;
    const int j = nt * 16 + r16;

    for (int head = 0; head < 16; ++head) {
        __syncthreads();
        for (int i = tid; i < 800; i += 256) {
            int row = i >> 5, c = (i & 31) << 3;
            *(uint4*)&Ql[row][c] =
                *(const uint4*)(g_qs + (long)head * 5128192L + ((long)bh * 25 + row) * 256 + c);
        }
        __syncthreads();
        f32x4 acc = {0.f, 0.f, 0.f, 0.f};
        #pragma unroll
        for (int k0 = 0; k0 < 256; k0 += 32) {
            short8 av = *(const short8*)&Ql[ia][k0 + ko * 8];
            short8 bv = *(const short8*)&Xl[jb][k0 + ko * 8];
            acc = __builtin_amdgcn_mfma_f32_16x16x32_bf16(av, bv, acc, 0, 0, 0);
        }
        if (j < 25) {
            #pragma unroll
            for (int reg = 0; reg < 4; ++reg) {
                int i2 = mt * 16 + ko * 4 + reg;
                if (i2 < 25)
                    g_buf[OFF_SHX + ((long)bh * 16 + head) * 700 + i2 * 28 + j] = acc[reg];
            }
        }
    }
}

// -------- SRC via MFMA from g_qs: SRC[zc][hh*20+s] = QS_row(t=20) . XC[s] ---
__global__ __launch_bounds__(256) void k_src()
{
    const int blk = blockIdx.x;              // 80 bc x 16 head
    const int bc = blk >> 4, head = blk & 15;
    const int b = bc / 5, c = bc % 5;
    __shared__ __align__(16) unsigned short sA[64][264];
    __shared__ __align__(16) unsigned short sB[32][264];
    const int tid = threadIdx.x;
    for (int i = tid; i < 2048; i += 256) {
        int m = i >> 5, cg = (i & 31) << 3;
        int hq = (m < 50) ? m : 49;
        *(uint4*)&sA[m][cg] = *(const uint4*)(g_qs + (long)head * 5128192L +
                               ((long)(b * 50 + hq) * 25 + 20 + c) * 256 + cg);
    }
    for (int i = tid; i < 1024; i += 256) {
        int s = i >> 5, cg = (i & 31) << 3;
        uint4 v = {0u, 0u, 0u, 0u};
        if (s < 20) v = *(const uint4*)(g_xcb + ((long)bc * 20 + s) * 256 + cg);
        *(uint4*)&sB[s][cg] = v;
    }
    __syncthreads();
    const int w = tid >> 6, lane = tid & 63;
    const int r16 = lane & 15, ko = lane >> 4;
    f32x4 acc0 = {0.f, 0.f, 0.f, 0.f};
    f32x4 acc1 = {0.f, 0.f, 0.f, 0.f};
    #pragma unroll
    for (int k0 = 0; k0 < 256; k0 += 32) {
        short8 av = *(const short8*)&sA[w * 16 + r16][k0 + ko * 8];
        short8 b0 = *(const short8*)&sB[r16][k0 + ko * 8];
        short8 b1 = *(const short8*)&sB[16 + r16][k0 + ko * 8];
        acc0 = __builtin_amdgcn_mfma_f32_16x16x32_bf16(av, b0, acc0, 0, 0, 0);
        acc1 = __builtin_amdgcn_mfma_f32_16x16x32_bf16(av, b1, acc1, 0, 0, 0);
    }
    const long zc = (long)(bc * 16 + head);
    #pragma unroll
    for (int reg = 0; reg < 4; ++reg) {
        int m = w * 16 + ko * 4 + reg;
        if (m < 50) {
            g_buf[OFF_SRC + zc * 1000 + m * 20 + r16] = acc0[reg];
            int s1 = 16 + r16;
            if (s1 < 20) g_buf[OFF_SRC + zc * 1000 + m * 20 + s1] = acc1[reg];
        }
    }
}

// -------- attention, wave-per-head, register softmax ------------------------
// Permuted indexing (consumers are permutation-invariant):
//   row/col r<20 -> t/s = r (cdd); 20<=r<40 -> t/s = r+1 (his); r=40 -> 20 (mix)
__global__ __launch_bounds__(256) void k_attn2()
{
    const int p = blockIdx.x;
    const int b = p / 250;
    const int c = (p / 50) % 5;
    const int hh = p % 50;
    const int bc = b * 5 + c;
    const int bh = b * 50 + hh;
    __shared__ __align__(16) unsigned short sV[41][264];   // VAL bf16 (permuted)
    __shared__ __align__(16) float sxv[4][41][16];         // per-wave xv
    const int tid = threadIdx.x;
    const int w = tid >> 6, lane = tid & 63;

    #pragma unroll 1
    for (int hi = 0; hi < 4; ++hi) {
        const int hd = w + hi * 4;
        const long z  = (long)(b * 16 + hd);
        const long zc = (long)(bc * 16 + hd);
        const long zh = (long)bh * 16 + hd;
        // stage xv (permuted rows)
        for (int i = lane; i < 656; i += 64) {
            int r = i >> 4, d = i & 15;
            float v;
            if (r < 20)      v = g_buf[OFF_XVC + ((long)bc * 20 + r) * 256 + hd * 16 + d];
            else if (r < 40) v = g_buf[OFF_XVH + ((long)bh * 20 + (r - 20)) * 256 + hd * 16 + d];
            else             v = g_buf[OFF_XVM + (long)p * 256 + hd * 16 + d];
            sxv[w][r][d] = v;
        }
        __builtin_amdgcn_wave_barrier();
        const int r = lane;
        if (r < 41) {
            // gather this row's 41 scores into registers
            const float *pA, *pB;
            float mid;
            if (r < 20) {
                pA = &g_buf[OFF_SCC + z * 10000 + (c * 20 + r) * 100 + c * 20];
                pB = &g_buf[OFF_CR1 + z * 100000 + (long)(c * 20 + r) * 1000 + hh * 20];
                mid = g_buf[OFF_SCX + zc * 1000 + r * 50 + hh];
            } else if (r < 40) {
                pA = &g_buf[OFF_CR2 + z * 100000 + (long)(hh * 20 + (r - 20)) * 100 + c * 20];
                pB = &g_buf[OFF_SHX + zh * 700 + (r - 20) * 28];
                mid = pB[20 + c];
            } else {
                pA = &g_buf[OFF_SRC + zc * 1000 + hh * 20];
                pB = &g_buf[OFF_SHX + zh * 700 + (20 + c) * 28];
                mid = pB[20 + c];
            }
            float rv[41];
            #pragma unroll
            for (int j = 0; j < 5; ++j) {
                float4 a4 = *(const float4*)(pA + 4 * j);
                rv[4 * j + 0] = a4.x; rv[4 * j + 1] = a4.y;
                rv[4 * j + 2] = a4.z; rv[4 * j + 3] = a4.w;
                float4 b4 = *(const float4*)(pB + 4 * j);
                rv[20 + 4 * j + 0] = b4.x; rv[20 + 4 * j + 1] = b4.y;
                rv[20 + 4 * j + 2] = b4.z; rv[20 + 4 * j + 3] = b4.w;
            }
            rv[40] = mid;
            // softmax in registers
            float mx = rv[40];
            #pragma unroll
            for (int j = 0; j < 20; ++j) mx = fmaxf(mx, fmaxf(rv[j], rv[j + 20]));
            float sum = 0.f;
            #pragma unroll
            for (int j = 0; j < 41; ++j) {
                float e = __expf((rv[j] - mx) * SCALE_C);
                rv[j] = e; sum += e;
            }
            const float inv = 1.f / sum;
            // PV from registers, xv broadcast from LDS
            float acc[16];
            #pragma unroll
            for (int d = 0; d < 16; ++d) acc[d] = 0.f;
            #pragma unroll
            for (int s = 0; s < 41; ++s) {
                const float4* xp = (const float4*)&sxv[w][s][0];
                float4 x0 = xp[0], x1 = xp[1], x2 = xp[2], x3 = xp[3];
                float pz = rv[s];
                acc[0]  = fmaf(pz, x0.x, acc[0]);  acc[1]  = fmaf(pz, x0.y, acc[1]);
                acc[2]  = fmaf(pz, x0.z, acc[2]);  acc[3]  = fmaf(pz, x0.w, acc[3]);
                acc[4]  = fmaf(pz, x1.x, acc[4]);  acc[5]  = fmaf(pz, x1.y, acc[5]);
                acc[6]  = fmaf(pz, x1.z, acc[6]);  acc[7]  = fmaf(pz, x1.w, acc[7]);
                acc[8]  = fmaf(pz, x2.x, acc[8]);  acc[9]  = fmaf(pz, x2.y, acc[9]);
                acc[10] = fmaf(pz, x2.z, acc[10]); acc[11] = fmaf(pz, x2.w, acc[11]);
                acc[12] = fmaf(pz, x3.x, acc[12]); acc[13] = fmaf(pz, x3.y, acc[13]);
                acc[14] = fmaf(pz, x3.z, acc[14]); acc[15] = fmaf(pz, x3.w, acc[15]);
            }
            #pragma unroll
            for (int j = 0; j < 8; ++j) {
                unsigned int lo = f2bf(acc[2 * j] * inv);
                unsigned int hi2 = f2bf(acc[2 * j + 1] * inv);
                *(unsigned int*)&sV[r][hd * 16 + 2 * j] = lo | (hi2 << 16);
            }
        }
        __builtin_amdgcn_wave_barrier();
    }
    __syncthreads();
    // coalesced bf16 write-out
    for (int i = tid; i < 1312; i += 256) {
        int rr = i >> 5, cc = (i & 31) << 3;
        uint4 v = *(const uint4*)&sV[rr][cc];
        *(uint4*)(g_valb + ((long)p * 41 + rr) * 256 + cc) = v;
    }
}

// -------- word-attn logits via MFMA --------
__global__ __launch_bounds__(256) void k_kq(const float* __restrict__ bk,
                                            const float* __restrict__ qw)
{
    const int blk = blockIdx.x;
    const long m0 = (long)blk * 64;
    __shared__ __align__(16) unsigned short sA[64][264];
    __shared__ __align__(16) unsigned short sWk[208][40];
    const int tid = threadIdx.x;

    for (int i = tid; i < 2048; i += 256) {
        int rloc = i >> 5, cg = (i & 31) << 3;
        long grow = m0 + rloc; if (grow > 163999L) grow = 163999L;
        *(uint4*)&sA[rloc][cg] = *(const uint4*)(g_valb + grow * 256 + cg);
    }

    const int w = tid >> 6, lane = tid & 63;
    const int r16 = lane & 15, ko = lane >> 4;

    f32x4 acc[13];
    #pragma unroll
    for (int j = 0; j < 13; ++j) acc[j] = (f32x4){0.f, 0.f, 0.f, 0.f};

    for (int kk = 0; kk < 8; ++kk) {
        __syncthreads();
        for (int i = tid; i < 832; i += 256) {
            int n = i >> 2, cg = (i & 3) << 3;
            *(uint4*)&sWk[n][cg] = *(const uint4*)(g_wkt + (long)n * 256 + kk * 32 + cg);
        }
        __syncthreads();
        short8 av = *(const short8*)&sA[w * 16 + r16][kk * 32 + ko * 8];
        #pragma unroll
        for (int j = 0; j < 13; ++j) {
            short8 bv = *(const short8*)&sWk[j * 16 + r16][ko * 8];
            acc[j] = __builtin_amdgcn_mfma_f32_16x16x32_bf16(av, bv, acc[j], 0, 0, 0);
        }
    }

    float s0 = 0.f, s1 = 0.f, s2 = 0.f, s3 = 0.f;
    #pragma unroll
    for (int j = 0; j < 13; ++j) {
        int cj = j * 16 + r16;
        float bkv = (cj < 200) ? bk[cj] : 0.f;
        float qwv = (cj < 200) ? qw[cj] : 0.f;
        s0 = fmaf(tanhf(acc[j][0] + bkv), qwv, s0);
        s1 = fmaf(tanhf(acc[j][1] + bkv), qwv, s1);
        s2 = fmaf(tanhf(acc[j][2] + bkv), qwv, s2);
        s3 = fmaf(tanhf(acc[j][3] + bkv), qwv, s3);
    }
    #pragma unroll
    for (int off = 1; off < 16; off <<= 1) {
        s0 += __shfl_xor(s0, off, 64);
        s1 += __shfl_xor(s1, off, 64);
        s2 += __shfl_xor(s2, off, 64);
        s3 += __shfl_xor(s3, off, 64);
    }
    if ((lane & 15) == 0) {
        long rbase = m0 + w * 16 + ko * 4;
        if (rbase + 0 < 164000L) g_kq[rbase + 0] = s0;
        if (rbase + 1 < 164000L) g_kq[rbase + 1] = s1;
        if (rbase + 2 < 164000L) g_kq[rbase + 2] = s2;
        if (rbase + 3 < 164000L) g_kq[rbase + 3] = s3;
    }
}

// -------- per-pair: softmax(kq*SCALE) over t, REP = w^T VAL --------
__global__ __launch_bounds__(256) void k_rep()
{
    const int p = blockIdx.x, tid = threadIdx.x;
    __shared__ __align__(16) unsigned short sval[41 * 256];
    __shared__ float skq[41];
    for (int i = tid; i < 1312; i += 256)
        ((uint4*)sval)[i] = ((const uint4*)(g_valb + (long)p * 41 * 256))[i];
    if (tid < 64) {
        float v = (tid < 41) ? g_kq[(long)p * 41 + tid] * SCALE_C : -1e30f;
        float m = v;
        #pragma unroll
        for (int off = 32; off > 0; off >>= 1) m = fmaxf(m, __shfl_xor(m, off, 64));
        float e = (tid < 41) ? __expf(v - m) : 0.f;
        float sum = e;
        #pragma unroll
        for (int off = 32; off > 0; off >>= 1) sum += __shfl_xor(sum, off, 64);
        if (tid < 41) skq[tid] = e / sum;
    }
    __syncthreads();
    float r = 0.f;
    for (int t = 0; t < 41; ++t) r = fmaf(skq[t], bf2f(sval[t * 256 + tid]), r);
    g_buf[OFF_REP + (long)p * 256 + tid] = r;
}

// -------- final: mean over HIS, .Wl + bl, log_softmax over CDD --------
__global__ __launch_bounds__(256) void k_final(const float* __restrict__ Wl,
                                               const float* __restrict__ bl,
                                               float* __restrict__ out)
{
    const int b = blockIdx.x, tid = threadIdx.x;
    __shared__ float ssum[4];
    __shared__ float sc5[5];
    float wl = Wl[tid];
    for (int c = 0; c < 5; ++c) {
        float fv = 0.f;
        const long base = OFF_REP + ((long)(b * 5 + c) * 50) * 256 + tid;
        for (int h = 0; h < 50; ++h) fv += g_buf[base + (long)h * 256];
        float v = fv * (1.0f / 50.0f) * wl;
        #pragma unroll
        for (int off = 32; off > 0; off >>= 1) v += __shfl_down(v, off, 64);
        if ((tid & 63) == 0) ssum[tid >> 6] = v;
        __syncthreads();
        if (tid == 0) sc5[c] = ssum[0] + ssum[1] + ssum[2] + ssum[3] + bl[0];
        __syncthreads();
    }
    if (tid == 0) {
        float m = -1e30f;
        for (int c = 0; c < 5; ++c) m = fmaxf(m, sc5[c]);
        float sum = 0.f;
        for (int c = 0; c < 5; ++c) sum += expf(sc5[c] - m);
        float lse = m + logf(sum);
        for (int c = 0; c < 5; ++c) out[b * 5 + c] = sc5[c] - lse;
    }
}

extern "C" void kernel_launch(void* const* d_in, const int* in_sizes, int n_in,
                              void* d_out, int out_size, void* d_ws, size_t ws_size,
                              hipStream_t stream)
{
    (void)in_sizes; (void)n_in; (void)d_ws; (void)ws_size; (void)out_size;
    const int*   cand  = (const int*)d_in[0];
    const int*   clk   = (const int*)d_in[1];
    const float* emb   = (const float*)d_in[2];
    const float* convw = (const float*)d_in[3];
    const float* convb = (const float*)d_in[4];
    const float* Wq    = (const float*)d_in[5];
    const float* bq    = (const float*)d_in[6];
    const float* Wv    = (const float*)d_in[7];
    const float* bv    = (const float*)d_in[8];
    const float* Wk    = (const float*)d_in[9];
    const float* bk    = (const float*)d_in[10];
    const float* qw    = (const float*)d_in[11];
    const float* Wl    = (const float*)d_in[12];
    const float* bl    = (const float*)d_in[13];
    float* out = (float*)d_out;

    k_wvr <<<256, 256, 0, stream>>>(Wv);
    k_conv<<<1280, 256, 0, stream>>>(cand, clk, emb, convw, convb);

    // bf16 conversions (needs XC/XH/XM from k_conv)
    k_cvt<<<25936, 256, 0, stream>>>(Wq, Wk);
    // QS[head] = XS @ Wq[head] + bq   (MFMA)
    k_qs<<<dim3(313, 4, 16), 256, 0, stream>>>(bq);
    // SHX = Q25 @ X25^T per (bh, head)  (MFMA)
    k_gram<<<800, 256, 0, stream>>>();
    // SRC from g_qs t=20 rows (MFMA) — replaces the QM f32 GEMM entirely
    k_src<<<1280, 256, 0, stream>>>();

    // projections (K=256 f32 GEMMs)
    gemm_k256<false><<<dim3(25, 4, 16), 256, 0, stream>>>(
        OFF_XC, 0, 0,  Wq, 0, 65536, 0,  bq, 0, 1, 256, 0,  OFF_QC, 409600, 256, 1600, 256);
    gemm_k256<true ><<<dim3(25, 4, 16), 256, 0, stream>>>(
        OFF_XC, 0, 0,  Wq, 0, 65536, 0,  nullptr, 0, 0, 0, 0,  OFF_QC2, 409600, 256, 1600, 256);
    gemm_k256<false><<<dim3(25, 4, 1), 256, 0, stream>>>(
        OFF_XC, 0, 0,  nullptr, OFF_WVR, 0, 0,  bv, 0, 1, 0, 0,  OFF_XVC, 0, 256, 1600, 256);
    gemm_k256<false><<<dim3(250, 4, 1), 256, 0, stream>>>(
        OFF_XH, 0, 0,  nullptr, OFF_WVR, 0, 0,  bv, 0, 1, 0, 0,  OFF_XVH, 0, 256, 16000, 256);
    gemm_k256<false><<<dim3(63, 4, 1), 256, 0, stream>>>(
        OFF_XM, 0, 0,  nullptr, OFF_WVR, 0, 0,  bv, 0, 1, 0, 0,  OFF_XVM, 0, 256, 4000, 256);
    k_bq<<<100, 256, 0, stream>>>(bq);

    // score blocks (NT f32 GEMMs)
    gemm_k256<true><<<dim3(2, 2, 256), 256, 0, stream>>>(
        OFF_QC, 409600, 25600,  nullptr, OFF_XC, 0, 25600,  nullptr, 0, 0, 0, 0,
        OFF_SCC, 10000, 100, 100, 100);
    gemm_k256<true><<<dim3(2, 16, 256), 256, 0, stream>>>(
        OFF_QC, 409600, 25600,  nullptr, OFF_XH, 0, 256000,  nullptr, 0, 0, 0, 0,
        OFF_CR1, 100000, 1000, 100, 1000);
    gemm_k256<true><<<dim3(16, 2, 256), 256, 0, stream>>>(
        OFF_XH, 0, 256000,  nullptr, OFF_QC2, 409600, 25600,  nullptr, OFF_BQC, 2, 1600, 100,
        OFF_CR2, 100000, 100, 1000, 100);
    gemm_k256<true><<<dim3(1, 1, 1280), 256, 0, stream>>>(
        OFF_QC, 409600, 5120,  nullptr, OFF_XM, 0, 12800,  nullptr, 0, 0, 0, 0,
        OFF_SCX, 1000, 50, 20, 50);

    k_attn2<<<4000, 256, 0, stream>>>();

    // word attention: MFMA logits + per-pair softmax/REP
    k_kq <<<2563, 256, 0, stream>>>(bk, qw);
    k_rep<<<4000, 256, 0, stream>>>();

    k_final<<<16, 256, 0, stream>>>(Wl, bl, out);
}

// Round 7
// 1039.729 us; speedup vs baseline: 3.0536x; 1.6750x over previous
//
#include <hip/hip_runtime.h>
#include <hip/hip_bf16.h>
#include <math.h>

// ---------------------------------------------------------------------------
// GCAModel forward, decomposed:
//   B=16 CDD=5 HIS=50 S=20 T=41 E=300 F=256 H=16 DV=16 QD=200
//   fusion = [cdd(0..19) | SEP@20 | his(21..40)]
//   XC [80][20][256] ; XH [800][20][256] ; XM [4000][256]  (conv outputs)
//   XS (bf16) rows: [0..19999] per-bh {XH 20 ; XM 5}, [20000..21599] XC, pad.
//   g_qs[head] = XS @ Wq[head] + bq   (bf16, all q-rows incl. QCS = XC side)
//   score blocks (all from g_qs x g_xs via MFMA):
//     SHX[bh][h][25(stride28)] = Q25.X25^T          (k_gram, f32)
//     CR1b[z][100][1000] = QCS.XH^T                 (k_cr1, bf16)
//     CR2b[z][1000][100] = QH.XC^T                  (k_cr2, bf16)
//     SCCd[zc][20][20] = QCS.XC^T diag, SCX = QCS.XM^T   (k_sccx, f32)
//     SRC[zc][50][20] = QM.XC^T                     (k_src, f32)
//   xv = x @ Wv_r + bv (f32 gemm) -> bf16 copy (k_cvtv)
//   k_attn2: block per (p, 4-head group), wave-per-head, row-in-registers
//     softmax+PV, VAL bf16 (permuted t/s order — consumers perm-invariant);
//   word-attn: kq = [tanh(VAL@Wk+bk)]@qw via MFMA (k_kq), softmax+REP (k_rep);
//   mean/LTR/log_softmax.
// ---------------------------------------------------------------------------

#define SCALE_C 0.05773502691896258f   // 1/sqrt(300)

typedef __attribute__((ext_vector_type(4))) float f32x4;
typedef __attribute__((ext_vector_type(8))) short short8;

static constexpr long QS_ROWS   = 21632L;           // 20000 bh-rows + 1600 XC + 32 pad
static constexpr long QS_STRIDE = QS_ROWS * 256;    // 5537792

static __device__ __forceinline__ unsigned short f2bf(float f)
{
    unsigned int u = __builtin_bit_cast(unsigned int, f);
    u = (u + 0x7fffu + ((u >> 16) & 1u)) >> 16;
    return (unsigned short)u;
}
static __device__ __forceinline__ float bf2f(unsigned short us)
{
    return __builtin_bit_cast(float, ((unsigned int)us) << 16);
}

// -------- static workspace (floats) --------
static constexpr long OFF_XC   = 0L;          // 80*20*256      = 409600
static constexpr long OFF_XH   = 409600L;     // 800*20*256     = 4096000
static constexpr long OFF_XM   = 4505600L;    // 4000*256       = 1024000
static constexpr long OFF_WVR  = 35046400L;   // 256*256        = 65536
static constexpr long OFF_XVC  = 35111936L;   // 1600*256       = 409600
static constexpr long OFF_XVH  = 35521536L;   // 16000*256      = 4096000
static constexpr long OFF_XVM  = 39617536L;   // 4000*256       = 1024000
static constexpr long OFF_SCC  = 40641536L;   // SCCd: 1280*400 = 512000 (reuse)
static constexpr long OFF_SRC  = 94401536L;   // 1280*50*20     = 1280000
static constexpr long OFF_SCX  = 95681536L;   // 1280*20*50     = 1280000
static constexpr long OFF_SHX  = 96961536L;   // 12800*700      = 8960000 (25 rows, stride 28)
static constexpr long OFF_REP  = 146945536L;  // 4000*256       = 1024000
static constexpr long TOTAL_F  = 147969536L;  // ~592 MB

__device__ __align__(16) float g_buf[TOTAL_F];

// bf16 side buffers for the MFMA paths
__device__ __align__(16) unsigned short g_xs[QS_ROWS * 256];       // 11.1 MB
__device__ __align__(16) unsigned short g_wqt[16L * 256 * 256];    // WqT[h][n][k]
__device__ __align__(16) unsigned short g_qs[16L * QS_STRIDE];     // 177 MB
__device__ __align__(16) unsigned short g_valb[164032L * 256];     // VAL bf16, 84 MB
__device__ __align__(16) unsigned short g_wkt[208L * 256];         // WkT[n][k]
__device__ __align__(16) unsigned short g_cr1[256L * 100 * 1000];  // CR1 bf16, 51 MB
__device__ __align__(16) unsigned short g_cr2[256L * 1000 * 100];  // CR2 bf16, 51 MB
__device__ __align__(16) unsigned short g_xvb[5529600L];           // xv bf16 (XVC|XVH|XVM)
__device__ __align__(16) float g_kq[164032L];                      // word-attn logits

// -------- Wv rearrange: WVR[g][h*16+d] = Wv[h][g][d] --------
__global__ __launch_bounds__(256) void k_wvr(const float* __restrict__ Wv)
{
    int i = blockIdx.x * 256 + threadIdx.x;      // 65536
    int g = i >> 8, n = i & 255;
    int h = n >> 4, d = n & 15;
    g_buf[OFF_WVR + i] = Wv[((long)h * 256 + g) * 16 + d];
}

// -------- conv (k=3, SAME, relu) --------
__global__ __launch_bounds__(256) void k_conv(const int* __restrict__ cand,
                                              const int* __restrict__ clk,
                                              const float* __restrict__ emb,
                                              const float* __restrict__ W,
                                              const float* __restrict__ cbias)
{
    __shared__ float se[22][300];
    const int bid = blockIdx.x, tid = threadIdx.x;
    int type, nrows, nctx;
    int b = 0, bc = 0, bh = 0, h0 = 0;
    if (bid < 80)       { type = 0; bc = bid;      b = bc / 5; nrows = 20; nctx = 22; }
    else if (bid < 880) { type = 1; bh = bid - 80;             nrows = 20; nctx = 22; }
    else { type = 2; int g = bid - 880; bc = g / 5; h0 = (g % 5) * 10; b = bc / 5; nrows = 10; nctx = 12; }

    for (int f = tid; f < nctx * 300; f += 256) {
        int r = f / 300, e = f - r * 300;
        int tok;
        if (type == 0)      tok = (r < 20) ? cand[bc * 20 + r] : (r == 20 ? 1 : -1);
        else if (type == 1) tok = (r == 0) ? 1 : (r <= 20 ? clk[bh * 20 + r - 1] : -1);
        else                tok = (r == 0) ? cand[bc * 20 + 19] : (r == 1 ? 1 : clk[((b * 50) + h0 + (r - 2)) * 20]);
        se[r][e] = (tok < 0) ? 0.0f : emb[(long)tok * 300 + e];
    }
    __syncthreads();

    const int lane = tid & 63, w = tid >> 6;
    int co[5][3];
    #pragma unroll
    for (int q = 0; q < 5; ++q) {
        int r = w + 4 * q; int rr = (r < nrows) ? r : 0;
        #pragma unroll
        for (int dt = 0; dt < 3; ++dt) {
            int idx;
            if (type == 0)      idx = (rr + dt == 0) ? 21 : rr + dt - 1;
            else if (type == 1) idx = rr + dt;
            else                idx = (dt == 0) ? 0 : (dt == 1 ? 1 : 2 + rr);
            co[q][dt] = idx;
        }
    }
    float acc[5][4] = {};
    for (int dt = 0; dt < 3; ++dt) {
        const float* wb = W + (long)(dt * 300) * 256 + lane * 4;
        for (int e = 0; e < 300; ++e) {
            float4 w4 = *(const float4*)(wb + (long)e * 256);
            #pragma unroll
            for (int q = 0; q < 5; ++q) {
                float a = se[co[q][dt]][e];
                acc[q][0] = fmaf(a, w4.x, acc[q][0]);
                acc[q][1] = fmaf(a, w4.y, acc[q][1]);
                acc[q][2] = fmaf(a, w4.z, acc[q][2]);
                acc[q][3] = fmaf(a, w4.w, acc[q][3]);
            }
        }
    }
    float4 b4 = *(const float4*)&cbias[lane * 4];
    #pragma unroll
    for (int q = 0; q < 5; ++q) {
        int r = w + 4 * q;
        if (r < nrows) {
            float4 o;
            o.x = fmaxf(acc[q][0] + b4.x, 0.f);
            o.y = fmaxf(acc[q][1] + b4.y, 0.f);
            o.z = fmaxf(acc[q][2] + b4.z, 0.f);
            o.w = fmaxf(acc[q][3] + b4.w, 0.f);
            long row;
            if (type == 0)      row = OFF_XC + ((long)bc * 20 + r) * 256;
            else if (type == 1) row = OFF_XH + ((long)bh * 20 + r) * 256;
            else                row = OFF_XM + ((long)(bc * 50 + h0 + r)) * 256;
            *(float4*)&g_buf[row + lane * 4] = o;
        }
    }
}

// -------- generic K=256 f32 GEMM (kept for xv projections only) --------
template<bool TB>
__global__ __launch_bounds__(256) void gemm_k256(
    long aOff, long aZH, long aZB,
    const float* Bext, long bOff, long bZH, long bZB,
    const float* biasExt, long biasOff, int biasKind, long sZH, long sZB,
    long cOff, long cZ, int ldc, int M, int N)
{
    const int z = blockIdx.z, head = z & 15, zo = z >> 4;
    const float* A = g_buf + aOff + (long)head * aZH + (long)zo * aZB;
    const float* B = (Bext ? Bext : (const float*)(g_buf + bOff)) + (long)head * bZH + (long)zo * bZB;
    const float* bias = nullptr;
    if (biasKind == 1)      bias = biasExt + (long)head * sZH + (long)zo * sZB;
    else if (biasKind == 2) bias = g_buf + biasOff + (long)head * sZH + (long)zo * sZB;
    float* C = g_buf + cOff + (long)z * cZ;

    const int m0 = blockIdx.x << 6, n0 = blockIdx.y << 6;
    __shared__ __align__(16) float As[32][68];
    __shared__ __align__(16) float Bs[32][68];
    const int tid = threadIdx.x;
    const int tx = tid & 15, ty = tid >> 4;
    float acc[4][4] = {};

    for (int kk = 0; kk < 256; kk += 32) {
        {
            int m = tid >> 2, ks = (tid & 3) << 3;
            int row = m0 + m; if (row > M - 1) row = M - 1;
            const float* ap = A + (long)row * 256 + kk + ks;
            float4 v0 = *(const float4*)ap;
            float4 v1 = *(const float4*)(ap + 4);
            As[ks + 0][m] = v0.x; As[ks + 1][m] = v0.y; As[ks + 2][m] = v0.z; As[ks + 3][m] = v0.w;
            As[ks + 4][m] = v1.x; As[ks + 5][m] = v1.y; As[ks + 6][m] = v1.z; As[ks + 7][m] = v1.w;
        }
        if (TB) {
            int n = tid >> 2, ks = (tid & 3) << 3;
            int col = n0 + n; if (col > N - 1) col = N - 1;
            const float* bp = B + (long)col * 256 + kk + ks;
            float4 v0 = *(const float4*)bp;
            float4 v1 = *(const float4*)(bp + 4);
            Bs[ks + 0][n] = v0.x; Bs[ks + 1][n] = v0.y; Bs[ks + 2][n] = v0.z; Bs[ks + 3][n] = v0.w;
            Bs[ks + 4][n] = v1.x; Bs[ks + 5][n] = v1.y; Bs[ks + 6][n] = v1.z; Bs[ks + 7][n] = v1.w;
        } else {
            int k = tid >> 3, ns = (tid & 7) << 3;
            const float* bp = B + (long)(kk + k) * 256 + n0 + ns;
            float4 v0 = *(const float4*)bp;
            float4 v1 = *(const float4*)(bp + 4);
            float* d = &Bs[k][ns];
            d[0] = v0.x; d[1] = v0.y; d[2] = v0.z; d[3] = v0.w;
            d[4] = v1.x; d[5] = v1.y; d[6] = v1.z; d[7] = v1.w;
        }
        __syncthreads();
        #pragma unroll
        for (int k = 0; k < 32; ++k) {
            float4 a4 = *(const float4*)&As[k][ty << 2];
            float4 b4 = *(const float4*)&Bs[k][tx << 2];
            float av[4] = {a4.x, a4.y, a4.z, a4.w};
            float bv_[4] = {b4.x, b4.y, b4.z, b4.w};
            #pragma unroll
            for (int i = 0; i < 4; ++i)
                #pragma unroll
                for (int j = 0; j < 4; ++j)
                    acc[i][j] = fmaf(av[i], bv_[j], acc[i][j]);
        }
        __syncthreads();
    }
    float cb[4] = {0.f, 0.f, 0.f, 0.f};
    if (bias) {
        #pragma unroll
        for (int j = 0; j < 4; ++j) { int col = n0 + (tx << 2) + j; if (col < N) cb[j] = bias[col]; }
    }
    #pragma unroll
    for (int i = 0; i < 4; ++i) {
        int row = m0 + (ty << 2) + i;
        if (row < M) {
            #pragma unroll
            for (int j = 0; j < 4; ++j) {
                int col = n0 + (tx << 2) + j;
                if (col < N) C[(long)row * ldc + col] = acc[i][j] + cb[j];
            }
        }
    }
}

// -------- bf16 conversion: XS (bh 25-blocks + XC rows + pad) + WqT + WkT ----
__global__ __launch_bounds__(256) void k_cvt(const float* __restrict__ Wq,
                                             const float* __restrict__ Wk)
{
    long i = (long)blockIdx.x * 256 + threadIdx.x;
    if (i < 5120000L) {                      // XS bh-blocks: 800*25*256
        int bh = (int)(i / 6400);
        int rem = (int)(i - (long)bh * 6400);
        int r = rem >> 8, e = rem & 255;
        float v;
        if (r < 20) v = g_buf[OFF_XH + ((long)bh * 20 + r) * 256 + e];
        else {
            int b = bh / 50, h = bh % 50;
            v = g_buf[OFF_XM + ((long)((b * 5 + (r - 20)) * 50 + h)) * 256 + e];
        }
        g_xs[i] = f2bf(v);
    } else if (i < 5529600L) {               // XC rows at 20000+: linear copy
        long j = i - 5120000L;
        g_xs[i] = f2bf(g_buf[OFF_XC + j]);
    } else if (i < 5537792L) {               // pad rows 21600..21631
        g_xs[i] = 0;
    } else if (i < 6586368L) {               // WqT[h][n][k] = Wq[h][k][n]
        long j = i - 5537792L;
        int h = (int)(j >> 16);
        int rem = (int)(j & 65535);
        int n = rem >> 8, k = rem & 255;
        g_wqt[j] = f2bf(Wq[(long)h * 65536 + k * 256 + n]);
    } else if (i < 6639616L) {               // WkT[n][k] = Wk[k][n], n>=200 -> 0
        long j = i - 6586368L;
        int n = (int)(j >> 8), k = (int)(j & 255);
        g_wkt[j] = (n < 200) ? f2bf(Wk[(long)k * 200 + n]) : 0;
    }
}

// -------- xv f32 -> bf16 (after XV gemms) --------
__global__ __launch_bounds__(256) void k_cvtv()
{
    long i4 = ((long)blockIdx.x * 256 + threadIdx.x) * 4;   // < 5529600
    float4 v = *(const float4*)&g_buf[OFF_XVC + i4];
    ushort4 o;
    o.x = f2bf(v.x); o.y = f2bf(v.y); o.z = f2bf(v.z); o.w = f2bf(v.w);
    *(ushort4*)&g_xvb[i4] = o;
}

// -------- MFMA batched GEMM: QS[head] = XS @ Wq[head] + bq (bf16 in/out) ----
__global__ __launch_bounds__(256) void k_qs(const float* __restrict__ bq)
{
    const int head = blockIdx.z;
    const int m0 = blockIdx.x << 6, n0 = blockIdx.y << 6;
    __shared__ __align__(16) unsigned short Al[64][32];
    __shared__ __align__(16) unsigned short Bl[64][32];
    const int tid = threadIdx.x;
    const int lrow = tid >> 2, lch = (tid & 3) << 3;
    const unsigned short* Ag = g_xs + (long)(m0 + lrow) * 256 + lch;
    const unsigned short* Bg = g_wqt + (long)head * 65536 + (long)(n0 + lrow) * 256 + lch;
    const int w = tid >> 6, lane = tid & 63;
    const int wm = w >> 1, wn = w & 1;
    const int r16 = lane & 15, ko = lane >> 4;

    f32x4 acc00 = {0.f, 0.f, 0.f, 0.f};
    f32x4 acc01 = {0.f, 0.f, 0.f, 0.f};
    f32x4 acc10 = {0.f, 0.f, 0.f, 0.f};
    f32x4 acc11 = {0.f, 0.f, 0.f, 0.f};

    for (int kk = 0; kk < 256; kk += 32) {
        uint4 a = *(const uint4*)(Ag + kk);
        uint4 b = *(const uint4*)(Bg + kk);
        __syncthreads();
        *(uint4*)&Al[lrow][lch] = a;
        *(uint4*)&Bl[lrow][lch] = b;
        __syncthreads();
        short8 av0 = *(const short8*)&Al[wm * 32 + r16][ko * 8];
        short8 av1 = *(const short8*)&Al[wm * 32 + 16 + r16][ko * 8];
        short8 bv0 = *(const short8*)&Bl[wn * 32 + r16][ko * 8];
        short8 bv1 = *(const short8*)&Bl[wn * 32 + 16 + r16][ko * 8];
        acc00 = __builtin_amdgcn_mfma_f32_16x16x32_bf16(av0, bv0, acc00, 0, 0, 0);
        acc01 = __builtin_amdgcn_mfma_f32_16x16x32_bf16(av0, bv1, acc01, 0, 0, 0);
        acc10 = __builtin_amdgcn_mfma_f32_16x16x32_bf16(av1, bv0, acc10, 0, 0, 0);
        acc11 = __builtin_amdgcn_mfma_f32_16x16x32_bf16(av1, bv1, acc11, 0, 0, 0);
    }
    const int n_0 = n0 + wn * 32 + r16;
    const int n_1 = n_0 + 16;
    const float bb0 = bq[head * 256 + n_0];
    const float bb1 = bq[head * 256 + n_1];
    const long qbase = (long)head * QS_STRIDE;
    const int mA = m0 + wm * 32 + ko * 4;
    const int mB = mA + 16;
    #pragma unroll
    for (int reg = 0; reg < 4; ++reg) {
        g_qs[qbase + (long)(mA + reg) * 256 + n_0] = f2bf(acc00[reg] + bb0);
        g_qs[qbase + (long)(mA + reg) * 256 + n_1] = f2bf(acc01[reg] + bb1);
        g_qs[qbase + (long)(mB + reg) * 256 + n_0] = f2bf(acc10[reg] + bb0);
        g_qs[qbase + (long)(mB + reg) * 256 + n_1] = f2bf(acc11[reg] + bb1);
    }
}

// -------- MFMA Gram per bh: SHX[bh][head] = Q25 @ X25^T (row stride 28) ----
__global__ __launch_bounds__(256) void k_gram()
{
    const int bh = blockIdx.x;
    __shared__ __align__(16) unsigned short Xl[25][264];
    __shared__ __align__(16) unsigned short Ql[25][264];
    const int tid = threadIdx.x;
    for (int i = tid; i < 800; i += 256) {
        int row = i >> 5, c = (i & 31) << 3;
        *(uint4*)&Xl[row][c] = *(const uint4*)(g_xs + ((long)bh * 25 + row) * 256 + c);
    }
    const int w = tid >> 6, lane = tid & 63;
    const int mt = w >> 1, nt = w & 1;
    const int r16 = lane & 15, ko = lane >> 4;
    int ia = mt * 16 + r16; if (ia > 24) ia = 24;
    int jb = nt * 16 + r16; if (jb > 24) jb = 24;
    const int j = nt * 16 + r16;

    for (int head = 0; head < 16; ++head) {
        __syncthreads();
        for (int i = tid; i < 800; i += 256) {
            int row = i >> 5, c = (i & 31) << 3;
            *(uint4*)&Ql[row][c] =
                *(const uint4*)(g_qs + (long)head * QS_STRIDE + ((long)bh * 25 + row) * 256 + c);
        }
        __syncthreads();
        f32x4 acc = {0.f, 0.f, 0.f, 0.f};
        #pragma unroll
        for (int k0 = 0; k0 < 256; k0 += 32) {
            short8 av = *(const short8*)&Ql[ia][k0 + ko * 8];
            short8 bv = *(const short8*)&Xl[jb][k0 + ko * 8];
            acc = __builtin_amdgcn_mfma_f32_16x16x32_bf16(av, bv, acc, 0, 0, 0);
        }
        if (j < 25) {
            #pragma unroll
            for (int reg = 0; reg < 4; ++reg) {
                int i2 = mt * 16 + ko * 4 + reg;
                if (i2 < 25)
                    g_buf[OFF_SHX + ((long)bh * 16 + head) * 700 + i2 * 28 + j] = acc[reg];
            }
        }
    }
}

// -------- CR1b[z][100][1000] = QCS(b) @ XH^T  (bf16 MFMA) --------
__global__ __launch_bounds__(256) void k_cr1()
{
    const int z = blockIdx.z, b = z >> 4, head = z & 15;
    const int m0 = blockIdx.x << 6, n0 = blockIdx.y << 6;
    __shared__ __align__(16) unsigned short Al[64][32];
    __shared__ __align__(16) unsigned short Bl[64][32];
    const int tid = threadIdx.x;
    const int lrow = tid >> 2, lch = (tid & 3) << 3;
    int am = m0 + lrow; if (am > 99) am = 99;
    const unsigned short* Ag = g_qs + (long)head * QS_STRIDE +
                               (long)(20000 + b * 100 + am) * 256 + lch;
    int jj = n0 + lrow; int hj = jj / 20, sj = jj - hj * 20;
    const unsigned short* Bg = g_xs + ((long)(b * 50 + hj) * 25 + sj) * 256 + lch;
    const int w = tid >> 6, lane = tid & 63;
    const int wm = w >> 1, wn = w & 1;
    const int r16 = lane & 15, ko = lane >> 4;

    f32x4 acc00 = {0.f,0.f,0.f,0.f}, acc01 = {0.f,0.f,0.f,0.f};
    f32x4 acc10 = {0.f,0.f,0.f,0.f}, acc11 = {0.f,0.f,0.f,0.f};
    for (int kk = 0; kk < 256; kk += 32) {
        uint4 a = *(const uint4*)(Ag + kk);
        uint4 b2 = *(const uint4*)(Bg + kk);
        __syncthreads();
        *(uint4*)&Al[lrow][lch] = a;
        *(uint4*)&Bl[lrow][lch] = b2;
        __syncthreads();
        short8 av0 = *(const short8*)&Al[wm * 32 + r16][ko * 8];
        short8 av1 = *(const short8*)&Al[wm * 32 + 16 + r16][ko * 8];
        short8 bv0 = *(const short8*)&Bl[wn * 32 + r16][ko * 8];
        short8 bv1 = *(const short8*)&Bl[wn * 32 + 16 + r16][ko * 8];
        acc00 = __builtin_amdgcn_mfma_f32_16x16x32_bf16(av0, bv0, acc00, 0, 0, 0);
        acc01 = __builtin_amdgcn_mfma_f32_16x16x32_bf16(av0, bv1, acc01, 0, 0, 0);
        acc10 = __builtin_amdgcn_mfma_f32_16x16x32_bf16(av1, bv0, acc10, 0, 0, 0);
        acc11 = __builtin_amdgcn_mfma_f32_16x16x32_bf16(av1, bv1, acc11, 0, 0, 0);
    }
    const int n_0 = n0 + wn * 32 + r16, n_1 = n_0 + 16;
    const int mA = m0 + wm * 32 + ko * 4, mB = mA + 16;
    const long cb = (long)z * 100000L;
    #pragma unroll
    for (int reg = 0; reg < 4; ++reg) {
        if (mA + reg < 100) {
            if (n_0 < 1000) g_cr1[cb + (long)(mA + reg) * 1000 + n_0] = f2bf(acc00[reg]);
            if (n_1 < 1000) g_cr1[cb + (long)(mA + reg) * 1000 + n_1] = f2bf(acc01[reg]);
        }
        if (mB + reg < 100) {
            if (n_0 < 1000) g_cr1[cb + (long)(mB + reg) * 1000 + n_0] = f2bf(acc10[reg]);
            if (n_1 < 1000) g_cr1[cb + (long)(mB + reg) * 1000 + n_1] = f2bf(acc11[reg]);
        }
    }
}

// -------- CR2b[z][1000][100] = QH @ XC(b)^T  (bf16 MFMA) --------
__global__ __launch_bounds__(256) void k_cr2()
{
    const int z = blockIdx.z, b = z >> 4, head = z & 15;
    const int m0 = blockIdx.x << 6, n0 = blockIdx.y << 6;
    __shared__ __align__(16) unsigned short Al[64][32];
    __shared__ __align__(16) unsigned short Bl[64][32];
    const int tid = threadIdx.x;
    const int lrow = tid >> 2, lch = (tid & 3) << 3;
    int mm = m0 + lrow; int hm = mm / 20, tm = mm - hm * 20;
    const unsigned short* Ag = g_qs + (long)head * QS_STRIDE +
                               ((long)(b * 50 + hm) * 25 + tm) * 256 + lch;
    const unsigned short* Bg = g_xs + (long)(20000 + b * 100 + n0 + lrow) * 256 + lch;
    const int w = tid >> 6, lane = tid & 63;
    const int wm = w >> 1, wn = w & 1;
    const int r16 = lane & 15, ko = lane >> 4;

    f32x4 acc00 = {0.f,0.f,0.f,0.f}, acc01 = {0.f,0.f,0.f,0.f};
    f32x4 acc10 = {0.f,0.f,0.f,0.f}, acc11 = {0.f,0.f,0.f,0.f};
    for (int kk = 0; kk < 256; kk += 32) {
        uint4 a = *(const uint4*)(Ag + kk);
        uint4 b2 = *(const uint4*)(Bg + kk);
        __syncthreads();
        *(uint4*)&Al[lrow][lch] = a;
        *(uint4*)&Bl[lrow][lch] = b2;
        __syncthreads();
        short8 av0 = *(const short8*)&Al[wm * 32 + r16][ko * 8];
        short8 av1 = *(const short8*)&Al[wm * 32 + 16 + r16][ko * 8];
        short8 bv0 = *(const short8*)&Bl[wn * 32 + r16][ko * 8];
        short8 bv1 = *(const short8*)&Bl[wn * 32 + 16 + r16][ko * 8];
        acc00 = __builtin_amdgcn_mfma_f32_16x16x32_bf16(av0, bv0, acc00, 0, 0, 0);
        acc01 = __builtin_amdgcn_mfma_f32_16x16x32_bf16(av0, bv1, acc01, 0, 0, 0);
        acc10 = __builtin_amdgcn_mfma_f32_16x16x32_bf16(av1, bv0, acc10, 0, 0, 0);
        acc11 = __builtin_amdgcn_mfma_f32_16x16x32_bf16(av1, bv1, acc11, 0, 0, 0);
    }
    const int n_0 = n0 + wn * 32 + r16, n_1 = n_0 + 16;
    const int mA = m0 + wm * 32 + ko * 4, mB = mA + 16;
    const long cb = (long)z * 100000L;
    #pragma unroll
    for (int reg = 0; reg < 4; ++reg) {
        if (mA + reg < 1000) {
            if (n_0 < 100) g_cr2[cb + (long)(mA + reg) * 100 + n_0] = f2bf(acc00[reg]);
            if (n_1 < 100) g_cr2[cb + (long)(mA + reg) * 100 + n_1] = f2bf(acc01[reg]);
        }
        if (mB + reg < 1000) {
            if (n_0 < 100) g_cr2[cb + (long)(mB + reg) * 100 + n_0] = f2bf(acc10[reg]);
            if (n_1 < 100) g_cr2[cb + (long)(mB + reg) * 100 + n_1] = f2bf(acc11[reg]);
        }
    }
}

// -------- SCCd[zc][20][20] = QCS.XC^T diag, SCX[zc][t][h] = QCS.XM^T --------
__global__ __launch_bounds__(256) void k_sccx()
{
    const int blk = blockIdx.x;              // zc = bc*16+head
    const int bc = blk >> 4, head = blk & 15;
    const int b = bc / 5, c = bc % 5;
    __shared__ __align__(16) unsigned short sQ[32][264];
    __shared__ __align__(16) unsigned short sX[80][264];
    const int tid = threadIdx.x;
    for (int i = tid; i < 1024; i += 256) {
        int row = i >> 5, cg = (i & 31) << 3;
        uint4 v = {0u,0u,0u,0u};
        if (row < 20)
            v = *(const uint4*)(g_qs + (long)head * QS_STRIDE +
                                (long)(20000 + bc * 20 + row) * 256 + cg);
        *(uint4*)&sQ[row][cg] = v;
    }
    for (int i = tid; i < 2560; i += 256) {
        int row = i >> 5, cg = (i & 31) << 3;
        uint4 v = {0u,0u,0u,0u};
        if (row < 20)
            v = *(const uint4*)(g_xs + (long)(20000 + bc * 20 + row) * 256 + cg);
        else if (row < 70) {
            int h = row - 20;
            v = *(const uint4*)(g_xs + ((long)(b * 50 + h) * 25 + 20 + c) * 256 + cg);
        }
        *(uint4*)&sX[row][cg] = v;
    }
    __syncthreads();
    const int w = tid >> 6, lane = tid & 63;
    const int r16 = lane & 15, ko = lane >> 4;
    const int ntN = (w == 0) ? 2 : 1;
    #pragma unroll 1
    for (int q = 0; q < ntN; ++q) {
        const int nt = w + q * 4;
        #pragma unroll
        for (int mt = 0; mt < 2; ++mt) {
            f32x4 acc = {0.f, 0.f, 0.f, 0.f};
            #pragma unroll
            for (int k0 = 0; k0 < 256; k0 += 32) {
                short8 av = *(const short8*)&sQ[mt * 16 + r16][k0 + ko * 8];
                short8 bv = *(const short8*)&sX[nt * 16 + r16][k0 + ko * 8];
                acc = __builtin_amdgcn_mfma_f32_16x16x32_bf16(av, bv, acc, 0, 0, 0);
            }
            const int j = nt * 16 + r16;
            #pragma unroll
            for (int reg = 0; reg < 4; ++reg) {
                int m = mt * 16 + ko * 4 + reg;
                if (m < 20) {
                    if (j < 20)
                        g_buf[OFF_SCC + (long)blk * 400 + m * 20 + j] = acc[reg];
                    else if (j < 70)
                        g_buf[OFF_SCX + (long)blk * 1000 + m * 50 + (j - 20)] = acc[reg];
                }
            }
        }
    }
}

// -------- SRC via MFMA from g_qs: SRC[zc][hh*20+s] = QM(t=20) . XC[s] ------
__global__ __launch_bounds__(256) void k_src()
{
    const int blk = blockIdx.x;              // 80 bc x 16 head
    const int bc = blk >> 4, head = blk & 15;
    const int b = bc / 5, c = bc % 5;
    __shared__ __align__(16) unsigned short sA[64][264];
    __shared__ __align__(16) unsigned short sB[32][264];
    const int tid = threadIdx.x;
    for (int i = tid; i < 2048; i += 256) {
        int m = i >> 5, cg = (i & 31) << 3;
        int hq = (m < 50) ? m : 49;
        *(uint4*)&sA[m][cg] = *(const uint4*)(g_qs + (long)head * QS_STRIDE +
                               ((long)(b * 50 + hq) * 25 + 20 + c) * 256 + cg);
    }
    for (int i = tid; i < 1024; i += 256) {
        int s = i >> 5, cg = (i & 31) << 3;
        uint4 v = {0u, 0u, 0u, 0u};
        if (s < 20) v = *(const uint4*)(g_xs + (long)(20000 + bc * 20 + s) * 256 + cg);
        *(uint4*)&sB[s][cg] = v;
    }
    __syncthreads();
    const int w = tid >> 6, lane = tid & 63;
    const int r16 = lane & 15, ko = lane >> 4;
    f32x4 acc0 = {0.f, 0.f, 0.f, 0.f};
    f32x4 acc1 = {0.f, 0.f, 0.f, 0.f};
    #pragma unroll
    for (int k0 = 0; k0 < 256; k0 += 32) {
        short8 av = *(const short8*)&sA[w * 16 + r16][k0 + ko * 8];
        short8 b0 = *(const short8*)&sB[r16][k0 + ko * 8];
        short8 b1 = *(const short8*)&sB[16 + r16][k0 + ko * 8];
        acc0 = __builtin_amdgcn_mfma_f32_16x16x32_bf16(av, b0, acc0, 0, 0, 0);
        acc1 = __builtin_amdgcn_mfma_f32_16x16x32_bf16(av, b1, acc1, 0, 0, 0);
    }
    const long zc = (long)blk;
    #pragma unroll
    for (int reg = 0; reg < 4; ++reg) {
        int m = w * 16 + ko * 4 + reg;
        if (m < 50) {
            g_buf[OFF_SRC + zc * 1000 + m * 20 + r16] = acc0[reg];
            int s1 = 16 + r16;
            if (s1 < 20) g_buf[OFF_SRC + zc * 1000 + m * 20 + s1] = acc1[reg];
        }
    }
}

// -------- attention: block per (p, 4-head group), wave-per-head ------------
// Permuted indexing: r<20 -> cdd, 20<=r<40 -> his, r=40 -> mix.
__global__ __launch_bounds__(256) void k_attn2()
{
    const int bid = blockIdx.x;              // p*4 + hg
    const int p = bid >> 2, hg = bid & 3;
    const int b = p / 250;
    const int c = (p / 50) % 5;
    const int hh = p % 50;
    const int bc = b * 5 + c;
    const int bh = b * 50 + hh;
    __shared__ __align__(16) unsigned short sV[41][72];
    __shared__ __align__(16) float sxv[4][41][16];
    const int tid = threadIdx.x, w = tid >> 6, lane = tid & 63;
    const int hd = hg * 4 + w;
    const long z  = (long)(b * 16 + hd);
    const long zc = (long)(bc * 16 + hd);
    const long zh = (long)bh * 16 + hd;

    // stage xv (bf16 -> f32 LDS), all 64 lanes
    for (int i = lane; i < 164; i += 64) {
        int r2 = i >> 2, q = i & 3;
        long src;
        if (r2 < 20)      src = ((long)bc * 20 + r2) * 256;
        else if (r2 < 40) src = 409600L + ((long)bh * 20 + (r2 - 20)) * 256;
        else              src = 4505600L + (long)p * 256;
        ushort4 v = *(const ushort4*)(g_xvb + src + hd * 16 + q * 4);
        sxv[w][r2][q * 4 + 0] = bf2f(v.x);
        sxv[w][r2][q * 4 + 1] = bf2f(v.y);
        sxv[w][r2][q * 4 + 2] = bf2f(v.z);
        sxv[w][r2][q * 4 + 3] = bf2f(v.w);
    }
    __builtin_amdgcn_wave_barrier();

    const int r = lane;
    if (r < 41) {
        float rv[41];
        if (r < 20) {
            const float* pA = &g_buf[OFF_SCC + zc * 400 + r * 20];
            #pragma unroll
            for (int j = 0; j < 5; ++j) {
                float4 a4 = *(const float4*)(pA + 4 * j);
                rv[4*j+0] = a4.x; rv[4*j+1] = a4.y; rv[4*j+2] = a4.z; rv[4*j+3] = a4.w;
            }
            const ushort4* pB = (const ushort4*)(g_cr1 + z * 100000L +
                                 (long)(c * 20 + r) * 1000 + hh * 20);
            #pragma unroll
            for (int j = 0; j < 5; ++j) {
                ushort4 v = pB[j];
                rv[20+4*j+0] = bf2f(v.x); rv[20+4*j+1] = bf2f(v.y);
                rv[20+4*j+2] = bf2f(v.z); rv[20+4*j+3] = bf2f(v.w);
            }
            rv[40] = g_buf[OFF_SCX + zc * 1000 + r * 50 + hh];
        } else {
            const float* pB;
            if (r < 40) {
                const ushort4* pA = (const ushort4*)(g_cr2 + z * 100000L +
                                     (long)(hh * 20 + (r - 20)) * 100 + c * 20);
                #pragma unroll
                for (int j = 0; j < 5; ++j) {
                    ushort4 v = pA[j];
                    rv[4*j+0] = bf2f(v.x); rv[4*j+1] = bf2f(v.y);
                    rv[4*j+2] = bf2f(v.z); rv[4*j+3] = bf2f(v.w);
                }
                pB = &g_buf[OFF_SHX + zh * 700 + (r - 20) * 28];
            } else {
                const float* pA = &g_buf[OFF_SRC + zc * 1000 + hh * 20];
                #pragma unroll
                for (int j = 0; j < 5; ++j) {
                    float4 a4 = *(const float4*)(pA + 4 * j);
                    rv[4*j+0] = a4.x; rv[4*j+1] = a4.y; rv[4*j+2] = a4.z; rv[4*j+3] = a4.w;
                }
                pB = &g_buf[OFF_SHX + zh * 700 + (20 + c) * 28];
            }
            #pragma unroll
            for (int j = 0; j < 5; ++j) {
                float4 b4 = *(const float4*)(pB + 4 * j);
                rv[20+4*j+0] = b4.x; rv[20+4*j+1] = b4.y;
                rv[20+4*j+2] = b4.z; rv[20+4*j+3] = b4.w;
            }
            rv[40] = pB[20 + c];
        }
        // softmax in registers
        float mx = rv[40];
        #pragma unroll
        for (int j = 0; j < 20; ++j) mx = fmaxf(mx, fmaxf(rv[j], rv[j + 20]));
        float sum = 0.f;
        #pragma unroll
        for (int j = 0; j < 41; ++j) {
            float e = __expf((rv[j] - mx) * SCALE_C);
            rv[j] = e; sum += e;
        }
        const float inv = 1.f / sum;
        // PV from registers, xv broadcast from LDS
        float acc[16];
        #pragma unroll
        for (int d = 0; d < 16; ++d) acc[d] = 0.f;
        #pragma unroll
        for (int s = 0; s < 41; ++s) {
            const float4* xp = (const float4*)&sxv[w][s][0];
            float4 x0 = xp[0], x1 = xp[1], x2 = xp[2], x3 = xp[3];
            float pz = rv[s];
            acc[0]  = fmaf(pz, x0.x, acc[0]);  acc[1]  = fmaf(pz, x0.y, acc[1]);
            acc[2]  = fmaf(pz, x0.z, acc[2]);  acc[3]  = fmaf(pz, x0.w, acc[3]);
            acc[4]  = fmaf(pz, x1.x, acc[4]);  acc[5]  = fmaf(pz, x1.y, acc[5]);
            acc[6]  = fmaf(pz, x1.z, acc[6]);  acc[7]  = fmaf(pz, x1.w, acc[7]);
            acc[8]  = fmaf(pz, x2.x, acc[8]);  acc[9]  = fmaf(pz, x2.y, acc[9]);
            acc[10] = fmaf(pz, x2.z, acc[10]); acc[11] = fmaf(pz, x2.w, acc[11]);
            acc[12] = fmaf(pz, x3.x, acc[12]); acc[13] = fmaf(pz, x3.y, acc[13]);
            acc[14] = fmaf(pz, x3.z, acc[14]); acc[15] = fmaf(pz, x3.w, acc[15]);
        }
        #pragma unroll
        for (int j = 0; j < 8; ++j) {
            unsigned int lo = f2bf(acc[2 * j] * inv);
            unsigned int hi2 = f2bf(acc[2 * j + 1] * inv);
            *(unsigned int*)&sV[r][w * 16 + 2 * j] = lo | (hi2 << 16);
        }
    }
    __syncthreads();
    // coalesced bf16 write-out of this block's 64 head-columns
    for (int i = tid; i < 328; i += 256) {
        int rr = i >> 3, cc = (i & 7) << 3;
        uint4 v = *(const uint4*)&sV[rr][cc];
        *(uint4*)(g_valb + ((long)p * 41 + rr) * 256 + hg * 64 + cc) = v;
    }
}

// -------- word-attn logits via MFMA --------
__global__ __launch_bounds__(256) void k_kq(const float* __restrict__ bk,
                                            const float* __restrict__ qw)
{
    const int blk = blockIdx.x;
    const long m0 = (long)blk * 64;
    __shared__ __align__(16) unsigned short sA[64][264];
    __shared__ __align__(16) unsigned short sWk[208][40];
    const int tid = threadIdx.x;

    for (int i = tid; i < 2048; i += 256) {
        int rloc = i >> 5, cg = (i & 31) << 3;
        long grow = m0 + rloc; if (grow > 163999L) grow = 163999L;
        *(uint4*)&sA[rloc][cg] = *(const uint4*)(g_valb + grow * 256 + cg);
    }

    const int w = tid >> 6, lane = tid & 63;
    const int r16 = lane & 15, ko = lane >> 4;

    f32x4 acc[13];
    #pragma unroll
    for (int j = 0; j < 13; ++j) acc[j] = (f32x4){0.f, 0.f, 0.f, 0.f};

    for (int kk = 0; kk < 8; ++kk) {
        __syncthreads();
        for (int i = tid; i < 832; i += 256) {
            int n = i >> 2, cg = (i & 3) << 3;
            *(uint4*)&sWk[n][cg] = *(const uint4*)(g_wkt + (long)n * 256 + kk * 32 + cg);
        }
        __syncthreads();
        short8 av = *(const short8*)&sA[w * 16 + r16][kk * 32 + ko * 8];
        #pragma unroll
        for (int j = 0; j < 13; ++j) {
            short8 bv = *(const short8*)&sWk[j * 16 + r16][ko * 8];
            acc[j] = __builtin_amdgcn_mfma_f32_16x16x32_bf16(av, bv, acc[j], 0, 0, 0);
        }
    }

    float s0 = 0.f, s1 = 0.f, s2 = 0.f, s3 = 0.f;
    #pragma unroll
    for (int j = 0; j < 13; ++j) {
        int cj = j * 16 + r16;
        float bkv = (cj < 200) ? bk[cj] : 0.f;
        float qwv = (cj < 200) ? qw[cj] : 0.f;
        s0 = fmaf(tanhf(acc[j][0] + bkv), qwv, s0);
        s1 = fmaf(tanhf(acc[j][1] + bkv), qwv, s1);
        s2 = fmaf(tanhf(acc[j][2] + bkv), qwv, s2);
        s3 = fmaf(tanhf(acc[j][3] + bkv), qwv, s3);
    }
    #pragma unroll
    for (int off = 1; off < 16; off <<= 1) {
        s0 += __shfl_xor(s0, off, 64);
        s1 += __shfl_xor(s1, off, 64);
        s2 += __shfl_xor(s2, off, 64);
        s3 += __shfl_xor(s3, off, 64);
    }
    if ((lane & 15) == 0) {
        long rbase = m0 + w * 16 + ko * 4;
        if (rbase + 0 < 164000L) g_kq[rbase + 0] = s0;
        if (rbase + 1 < 164000L) g_kq[rbase + 1] = s1;
        if (rbase + 2 < 164000L) g_kq[rbase + 2] = s2;
        if (rbase + 3 < 164000L) g_kq[rbase + 3] = s3;
    }
}

// -------- per-pair: softmax(kq*SCALE) over t, REP = w^T VAL --------
__global__ __launch_bounds__(256) void k_rep()
{
    const int p = blockIdx.x, tid = threadIdx.x;
    __shared__ __align__(16) unsigned short sval[41 * 256];
    __shared__ float skq[41];
    for (int i = tid; i < 1312; i += 256)
        ((uint4*)sval)[i] = ((const uint4*)(g_valb + (long)p * 41 * 256))[i];
    if (tid < 64) {
        float v = (tid < 41) ? g_kq[(long)p * 41 + tid] * SCALE_C : -1e30f;
        float m = v;
        #pragma unroll
        for (int off = 32; off > 0; off >>= 1) m = fmaxf(m, __shfl_xor(m, off, 64));
        float e = (tid < 41) ? __expf(v - m) : 0.f;
        float sum = e;
        #pragma unroll
        for (int off = 32; off > 0; off >>= 1) sum += __shfl_xor(sum, off, 64);
        if (tid < 41) skq[tid] = e / sum;
    }
    __syncthreads();
    float r = 0.f;
    for (int t = 0; t < 41; ++t) r = fmaf(skq[t], bf2f(sval[t * 256 + tid]), r);
    g_buf[OFF_REP + (long)p * 256 + tid] = r;
}

// -------- final: mean over HIS, .Wl + bl, log_softmax over CDD --------
__global__ __launch_bounds__(256) void k_final(const float* __restrict__ Wl,
                                               const float* __restrict__ bl,
                                               float* __restrict__ out)
{
    const int b = blockIdx.x, tid = threadIdx.x;
    __shared__ float ssum[4];
    __shared__ float sc5[5];
    float wl = Wl[tid];
    for (int c = 0; c < 5; ++c) {
        float fv = 0.f;
        const long base = OFF_REP + ((long)(b * 5 + c) * 50) * 256 + tid;
        for (int h = 0; h < 50; ++h) fv += g_buf[base + (long)h * 256];
        float v = fv * (1.0f / 50.0f) * wl;
        #pragma unroll
        for (int off = 32; off > 0; off >>= 1) v += __shfl_down(v, off, 64);
        if ((tid & 63) == 0) ssum[tid >> 6] = v;
        __syncthreads();
        if (tid == 0) sc5[c] = ssum[0] + ssum[1] + ssum[2] + ssum[3] + bl[0];
        __syncthreads();
    }
    if (tid == 0) {
        float m = -1e30f;
        for (int c = 0; c < 5; ++c) m = fmaxf(m, sc5[c]);
        float sum = 0.f;
        for (int c = 0; c < 5; ++c) sum += expf(sc5[c] - m);
        float lse = m + logf(sum);
        for (int c = 0; c < 5; ++c) out[b * 5 + c] = sc5[c] - lse;
    }
}

extern "C" void kernel_launch(void* const* d_in, const int* in_sizes, int n_in,
                              void* d_out, int out_size, void* d_ws, size_t ws_size,
                              hipStream_t stream)
{
    (void)in_sizes; (void)n_in; (void)d_ws; (void)ws_size; (void)out_size;
    const int*   cand  = (const int*)d_in[0];
    const int*   clk   = (const int*)d_in[1];
    const float* emb   = (const float*)d_in[2];
    const float* convw = (const float*)d_in[3];
    const float* convb = (const float*)d_in[4];
    const float* Wq    = (const float*)d_in[5];
    const float* bq    = (const float*)d_in[6];
    const float* Wv    = (const float*)d_in[7];
    const float* bv    = (const float*)d_in[8];
    const float* Wk    = (const float*)d_in[9];
    const float* bk    = (const float*)d_in[10];
    const float* qw    = (const float*)d_in[11];
    const float* Wl    = (const float*)d_in[12];
    const float* bl    = (const float*)d_in[13];
    float* out = (float*)d_out;

    k_wvr <<<256, 256, 0, stream>>>(Wv);
    k_conv<<<1280, 256, 0, stream>>>(cand, clk, emb, convw, convb);

    // bf16 conversions (needs XC/XH/XM from k_conv)
    k_cvt<<<25936, 256, 0, stream>>>(Wq, Wk);
    // QS[head] = XS @ Wq[head] + bq   (MFMA, M=21632 incl. QCS rows)
    k_qs<<<dim3(338, 4, 16), 256, 0, stream>>>(bq);
    // score blocks, all MFMA from bf16 operands
    k_gram<<<800, 256, 0, stream>>>();
    k_cr1 <<<dim3(2, 16, 256), 256, 0, stream>>>();
    k_cr2 <<<dim3(16, 2, 256), 256, 0, stream>>>();
    k_sccx<<<1280, 256, 0, stream>>>();
    k_src <<<1280, 256, 0, stream>>>();

    // xv projections (f32 GEMMs) + bf16 copy
    gemm_k256<false><<<dim3(25, 4, 1), 256, 0, stream>>>(
        OFF_XC, 0, 0,  nullptr, OFF_WVR, 0, 0,  bv, 0, 1, 0, 0,  OFF_XVC, 0, 256, 1600, 256);
    gemm_k256<false><<<dim3(250, 4, 1), 256, 0, stream>>>(
        OFF_XH, 0, 0,  nullptr, OFF_WVR, 0, 0,  bv, 0, 1, 0, 0,  OFF_XVH, 0, 256, 16000, 256);
    gemm_k256<false><<<dim3(63, 4, 1), 256, 0, stream>>>(
        OFF_XM, 0, 0,  nullptr, OFF_WVR, 0, 0,  bv, 0, 1, 0, 0,  OFF_XVM, 0, 256, 4000, 256);
    k_cvtv<<<5400, 256, 0, stream>>>();

    // attention (16000 blocks: p x 4-head groups)
    k_attn2<<<16000, 256, 0, stream>>>();

    // word attention: MFMA logits + per-pair softmax/REP
    k_kq <<<2563, 256, 0, stream>>>(bk, qw);
    k_rep<<<4000, 256, 0, stream>>>();

    k_final<<<16, 256, 0, stream>>>(Wl, bl, out);
}